// Round 7
// baseline (590.476 us; speedup 1.0000x reference)
//
#include <hip/hip_runtime.h>
#include <cstdint>
#include <cstddef>

#define HW 14400
#define WIDTH 120
#define S_TOT 110

typedef unsigned short u16;
typedef __attribute__((ext_vector_type(8))) short bf16x8;
typedef __attribute__((ext_vector_type(4))) float f32x4;

__device__ __forceinline__ u16 f2bf(float x) {
  unsigned u = __float_as_uint(x);
  unsigned r = (u + 0x7fffu + ((u >> 16) & 1u)) >> 16;
  return (u16)r;
}
__device__ __forceinline__ float bf2f(u16 h) {
  return __uint_as_float((unsigned)h << 16);
}

__device__ __forceinline__ void async16(void* lds, const void* g) {
  __builtin_amdgcn_global_load_lds(
      (const __attribute__((address_space(1))) void*)g,
      (__attribute__((address_space(3))) void*)lds, 16, 0, 0);
}

__device__ __forceinline__ float pool_scale(int s) {
  return (s == 0) ? (1.f / 14400.f)
         : (s < 10) ? (1.f / 1600.f)
         : (s < 46) ? (1.f / 400.f)
                    : (1.f / 225.f);
}

// ---------------------------------------------------------------------------
// Pyramid pooling (fallback only): in [nplanes][14400] -> out [nplanes][110]
// ---------------------------------------------------------------------------
__global__ __launch_bounds__(256) void pool_kernel(const float* __restrict__ in,
                                                   float* __restrict__ outp) {
  __shared__ float colsum[2880];
  __shared__ float part[576];
  const float* plane = in + (size_t)blockIdx.x * HW;
  int t = threadIdx.x;
  for (int i = t; i < 2880; i += 256) {
    int by = i / 120, x = i - by * 120;
    const float* p0 = plane + (by * 5) * WIDTH + x;
    colsum[i] = p0[0] + p0[WIDTH] + p0[2 * WIDTH] + p0[3 * WIDTH] + p0[4 * WIDTH];
  }
  __syncthreads();
  for (int bb = t; bb < 576; bb += 256) {
    int by = bb / 24, bx = bb - by * 24;
    const float* c = &colsum[by * 120 + bx * 5];
    part[bb] = c[0] + c[1] + c[2] + c[3] + c[4];
  }
  __syncthreads();
  if (t < S_TOT) {
    float s = 0.f;
    if (t == 0) {
      for (int i = 0; i < 576; ++i) s += part[i];
      s *= (1.f / 14400.f);
    } else if (t < 10) {
      int idx = t - 1, i = idx / 3, j = idx % 3;
      for (int a = 0; a < 8; ++a)
        for (int c = 0; c < 8; ++c) s += part[(i * 8 + a) * 24 + (j * 8 + c)];
      s *= (1.f / 1600.f);
    } else if (t < 46) {
      int idx = t - 10, i = idx / 6, j = idx % 6;
      for (int a = 0; a < 4; ++a)
        for (int c = 0; c < 4; ++c) s += part[(i * 4 + a) * 24 + (j * 4 + c)];
      s *= (1.f / 400.f);
    } else {
      int idx = t - 46, i = idx / 8, j = idx % 8;
      for (int a = 0; a < 3; ++a)
        for (int c = 0; c < 3; ++c) s += part[(i * 3 + a) * 24 + (j * 3 + c)];
      s *= (1.f / 225.f);
    }
    outp[(size_t)blockIdx.x * S_TOT + t] = s;
  }
}

// ---------------------------------------------------------------------------
// Split fp32 weight -> bf16 hi/lo (elementwise)
// ---------------------------------------------------------------------------
__global__ __launch_bounds__(256) void convert_w(const float* __restrict__ in,
                                                 u16* __restrict__ hi,
                                                 u16* __restrict__ lo, int n) {
  int i = blockIdx.x * 256 + threadIdx.x;
  if (i < n) {
    float v = in[i];
    u16 h = f2bf(v);
    hi[i] = h;
    lo[i] = f2bf(v - bf2f(h));
  }
}

// ---------------------------------------------------------------------------
// X [b][CIN][14400] fp32 -> XT hi/lo [b][14400][CIN] bf16 (transpose + split)
// + OPTIONAL fused pyramid-pool partial sums: psum[b][110][CIN] (atomicAdd).
//   Per thread: channel c = t&63, 16 pixels; running-bin accumulation with
//   flush-on-change (bins are contiguous in pixel order within a row).
// ---------------------------------------------------------------------------
template <int CIN>
__global__ __launch_bounds__(256) void convert_t(const float* __restrict__ X,
                                                 u16* __restrict__ xth,
                                                 u16* __restrict__ xtl,
                                                 float* __restrict__ psum) {
  __shared__ float ls[64][65];
  int b = blockIdx.z;
  int n0 = blockIdx.x * 64, k0 = blockIdx.y * 64;
  int t = threadIdx.x;
  int rt = t >> 4, c4 = (t & 15) * 4;
#pragma unroll
  for (int rr = 0; rr < 4; ++rr) {
    int kk = rr * 16 + rt;
    float4 v = *(const float4*)&X[((size_t)(b * CIN + k0 + kk)) * HW + n0 + c4];
    ls[kk][c4] = v.x; ls[kk][c4 + 1] = v.y; ls[kk][c4 + 2] = v.z; ls[kk][c4 + 3] = v.w;
  }
  __syncthreads();
#pragma unroll
  for (int rr = 0; rr < 4; ++rr) {
    int nn = rr * 16 + rt;
    float v0 = ls[c4 + 0][nn], v1 = ls[c4 + 1][nn], v2 = ls[c4 + 2][nn], v3 = ls[c4 + 3][nn];
    ushort4 oh, ol;
    oh.x = f2bf(v0); ol.x = f2bf(v0 - bf2f(oh.x));
    oh.y = f2bf(v1); ol.y = f2bf(v1 - bf2f(oh.y));
    oh.z = f2bf(v2); ol.z = f2bf(v2 - bf2f(oh.z));
    oh.w = f2bf(v3); ol.w = f2bf(v3 - bf2f(oh.w));
    size_t idx = ((size_t)(b * HW + n0 + nn)) * CIN + k0 + c4;
    *(ushort4*)&xth[idx] = oh;
    *(ushort4*)&xtl[idx] = ol;
  }
  if (psum) {
    int c = t & 63, g = t >> 6;  // channel-in-tile, pixel group (4 x 16)
    float s1 = 0.f, s3 = 0.f, s6 = 0.f, s8 = 0.f;
    int b3 = -1, b6 = -1, b8 = -1;
    float* base = psum + (size_t)b * 110 * CIN + k0 + c;
    for (int i = 0; i < 16; ++i) {
      int px = g * 16 + i;
      int n = n0 + px;
      int row = n / 120, col = n - row * 120;
      int i3 = 1 + (row / 40) * 3 + col / 40;
      int i6 = 10 + (row / 20) * 6 + col / 20;
      int i8 = 46 + (row / 15) * 8 + col / 15;
      float v = ls[c][px];
      s1 += v;
      if (i3 != b3) { if (b3 >= 0) atomicAdd(base + (size_t)b3 * CIN, s3); s3 = 0.f; b3 = i3; }
      s3 += v;
      if (i6 != b6) { if (b6 >= 0) atomicAdd(base + (size_t)b6 * CIN, s6); s6 = 0.f; b6 = i6; }
      s6 += v;
      if (i8 != b8) { if (b8 >= 0) atomicAdd(base + (size_t)b8 * CIN, s8); s8 = 0.f; b8 = i8; }
      s8 += v;
    }
    atomicAdd(base, s1);
    atomicAdd(base + (size_t)b3 * CIN, s3);
    atomicAdd(base + (size_t)b6 * CIN, s6);
    atomicAdd(base + (size_t)b8 * CIN, s8);
  }
}

// ---------------------------------------------------------------------------
// Split-bf16 MFMA GEMM v7:  epi( sum_k A[m][k]*B[b][n][k] )
//  Main loop identical to harness-verified v5/v6 (3-slot ring, counted
//  vmcnt(5), setprio). Epilogue (BNRELU + Th):
//   - optional C store (C==nullptr when fp32 kq is not needed)
//   - split-bf16 LDS transpose -> coalesced kqT stores (as v6)
//   - NEW: fused pyramid-pool partial sums from the LDS transpose buffer
//     (reconstruct v = hi + lo, err <= 2^-18) -> atomicAdd PS[b][110][M_TOT]
// ---------------------------------------------------------------------------
template <int K, int M_TOT, bool BNRELU>
__global__ __launch_bounds__(512, 2) void gemm_mfma(
    const u16* __restrict__ Ah, const u16* __restrict__ Al,
    const u16* __restrict__ Bh, const u16* __restrict__ Bl,
    float* __restrict__ C,
    const float* __restrict__ p0, const float* __restrict__ p1,
    const float* __restrict__ p2, const float* __restrict__ p3,
    const float* __restrict__ p4,
    u16* __restrict__ Th, u16* __restrict__ Tl,
    float* __restrict__ PS) {
  constexpr int NSTEP = K / 32;
  // unified: ring sA = smem[0..24576), ring sB = smem[24576..61440)
  // epilogue transpose: hi = smem[0..26112), lo = smem[26112..52224)
  __shared__ alignas(16) u16 smem[61440];

  int t = threadIdx.x, w = t >> 6, l = t & 63;
  int wm = w >> 2, wn = w & 3;
  int b = blockIdx.z;
  int n0 = blockIdx.x * 192;
  int m0 = blockIdx.y * 128;

  int fr = l & 15, fkc = l >> 4;
  const size_t bOff = (size_t)b * HW;

  auto stage = [&](int ks, int slot) {
    int k0 = ks * 32;
#pragma unroll
    for (int c = 0; c < 5; ++c) {
      int i = w * 5 + c;
      const u16* g;
      u16* d;
      if (i < 8) {
        g = Ah + (size_t)(m0 + i * 16 + fr) * K + k0 + fkc * 8;
        d = &smem[slot * 8192 + i * 512];
      } else if (i < 16) {
        g = Al + (size_t)(m0 + (i - 8) * 16 + fr) * K + k0 + fkc * 8;
        d = &smem[slot * 8192 + i * 512];
      } else if (i < 28) {
        g = Bh + (bOff + n0 + (i - 16) * 16 + fr) * (size_t)K + k0 + fkc * 8;
        d = &smem[24576 + slot * 12288 + (i - 16) * 512];
      } else {
        g = Bl + (bOff + n0 + (i - 28) * 16 + fr) * (size_t)K + k0 + fkc * 8;
        d = &smem[24576 + slot * 12288 + (i - 16) * 512];
      }
      async16(d, g);
    }
  };

  f32x4 acc[4][3];
#pragma unroll
  for (int i = 0; i < 4; ++i)
#pragma unroll
    for (int j = 0; j < 3; ++j) acc[i][j] = (f32x4){0.f, 0.f, 0.f, 0.f};

  stage(0, 0);
  stage(1, 1);

  for (int ks = 0; ks < NSTEP; ++ks) {
    if (ks + 1 < NSTEP)
      asm volatile("s_waitcnt vmcnt(5)" ::: "memory");
    else
      asm volatile("s_waitcnt vmcnt(0)" ::: "memory");
    __builtin_amdgcn_s_barrier();
    __builtin_amdgcn_sched_barrier(0);

    if (ks + 2 < NSTEP) stage(ks + 2, (ks + 2) % 3);

    int cur = ks % 3;
    bf16x8 bh[3], bl[3];
#pragma unroll
    for (int nt = 0; nt < 3; ++nt) {
      bh[nt] = *(const bf16x8*)&smem[24576 + cur * 12288 + (wn * 3 + nt) * 512 + l * 8];
      bl[nt] = *(const bf16x8*)&smem[24576 + cur * 12288 + (12 + wn * 3 + nt) * 512 + l * 8];
    }
    bf16x8 ah[4], al[4];
#pragma unroll
    for (int mt = 0; mt < 4; ++mt) {
      ah[mt] = *(const bf16x8*)&smem[cur * 8192 + (wm * 4 + mt) * 512 + l * 8];
      al[mt] = *(const bf16x8*)&smem[cur * 8192 + (8 + wm * 4 + mt) * 512 + l * 8];
    }
    __builtin_amdgcn_s_setprio(1);
#pragma unroll
    for (int mt = 0; mt < 4; ++mt)
#pragma unroll
      for (int nt = 0; nt < 3; ++nt) {
        acc[mt][nt] = __builtin_amdgcn_mfma_f32_16x16x32_bf16(ah[mt], bh[nt], acc[mt][nt], 0, 0, 0);
        acc[mt][nt] = __builtin_amdgcn_mfma_f32_16x16x32_bf16(ah[mt], bl[nt], acc[mt][nt], 0, 0, 0);
        acc[mt][nt] = __builtin_amdgcn_mfma_f32_16x16x32_bf16(al[mt], bh[nt], acc[mt][nt], 0, 0, 0);
      }
    __builtin_amdgcn_s_setprio(0);
  }

  __syncthreads();  // all ring LDS reads done before epilogue reuses smem

  int q4 = (l >> 4) * 4;
#pragma unroll
  for (int mt = 0; mt < 4; ++mt) {
    int mb = m0 + (wm * 4 + mt) * 16 + q4;
    float iv[4], ad[4];
    if (BNRELU) {
      float4 g0 = *(const float4*)&p0[mb];
      float4 g1 = *(const float4*)&p1[mb];
      float4 g2 = *(const float4*)&p2[mb];
      float4 g3 = *(const float4*)&p3[mb];
      float4 g4 = *(const float4*)&p4[mb];
      iv[0] = g1.x * rsqrtf(g4.x + 1e-5f);
      iv[1] = g1.y * rsqrtf(g4.y + 1e-5f);
      iv[2] = g1.z * rsqrtf(g4.z + 1e-5f);
      iv[3] = g1.w * rsqrtf(g4.w + 1e-5f);
      ad[0] = (g0.x - g3.x) * iv[0] + g2.x;
      ad[1] = (g0.y - g3.y) * iv[1] + g2.y;
      ad[2] = (g0.z - g3.z) * iv[2] + g2.z;
      ad[3] = (g0.w - g3.w) * iv[3] + g2.w;
    } else {
      float4 g0 = *(const float4*)&p0[mb];
      ad[0] = g0.x; ad[1] = g0.y; ad[2] = g0.z; ad[3] = g0.w;
    }
#pragma unroll
    for (int nt = 0; nt < 3; ++nt) {
      int n = n0 + (wn * 3 + nt) * 16 + fr;
      float v[4];
#pragma unroll
      for (int r = 0; r < 4; ++r) {
        float x = acc[mt][nt][r];
        v[r] = BNRELU ? fmaxf(x * iv[r] + ad[r], 0.f) : x + ad[r];
        if (C) C[((size_t)(b * M_TOT) + mb + r) * HW + n] = v[r];
      }
      if (BNRELU && Th) {
        ushort4 hh, ll;
        hh.x = f2bf(v[0]); ll.x = f2bf(v[0] - bf2f(hh.x));
        hh.y = f2bf(v[1]); ll.y = f2bf(v[1] - bf2f(hh.y));
        hh.z = f2bf(v[2]); ll.z = f2bf(v[2] - bf2f(hh.z));
        hh.w = f2bf(v[3]); ll.w = f2bf(v[3] - bf2f(hh.w));
        int nl = (wn * 3 + nt) * 16 + fr;
        int ml = (wm * 4 + mt) * 16 + q4;
        *(ushort4*)&smem[nl * 136 + ml] = hh;
        *(ushort4*)&smem[26112 + nl * 136 + ml] = ll;
      }
    }
  }
  if (BNRELU && Th) {
    __syncthreads();
    // coalesced kqT stores: row = pixel (n), 128 u16 of channels
#pragma unroll
    for (int it = 0; it < 6; ++it) {
      int row = it * 32 + (t >> 4);
      int c8 = (t & 15) * 8;
      size_t go = (bOff + n0 + row) * (size_t)M_TOT + m0 + c8;
      *(bf16x8*)&Th[go] = *(const bf16x8*)&smem[row * 136 + c8];
      *(bf16x8*)&Tl[go] = *(const bf16x8*)&smem[26112 + row * 136 + c8];
    }
    if (PS) {
      // fused pyramid pooling from the LDS transpose buffer
      int c = t & 127, g = t >> 7;  // channel, pixel group (4 x 48)
      float s1 = 0.f, s3 = 0.f, s6 = 0.f, s8 = 0.f;
      int b3 = -1, b6 = -1, b8 = -1;
      float* base = PS + (size_t)b * 110 * M_TOT + m0 + c;
      for (int i = 0; i < 48; ++i) {
        int px = g * 48 + i;
        int n = n0 + px;
        int row = n / 120, col = n - row * 120;
        int i3 = 1 + (row / 40) * 3 + col / 40;
        int i6 = 10 + (row / 20) * 6 + col / 20;
        int i8 = 46 + (row / 15) * 8 + col / 15;
        float v = bf2f(smem[px * 136 + c]) + bf2f(smem[26112 + px * 136 + c]);
        s1 += v;
        if (i3 != b3) { if (b3 >= 0) atomicAdd(base + (size_t)b3 * M_TOT, s3); s3 = 0.f; b3 = i3; }
        s3 += v;
        if (i6 != b6) { if (b6 >= 0) atomicAdd(base + (size_t)b6 * M_TOT, s6); s6 = 0.f; b6 = i6; }
        s6 += v;
        if (i8 != b8) { if (b8 >= 0) atomicAdd(base + (size_t)b8 * M_TOT, s8); s8 = 0.f; b8 = i8; }
        s8 += v;
      }
      atomicAdd(base, s1);
      atomicAdd(base + (size_t)b3 * M_TOT, s3);
      atomicAdd(base + (size_t)b6 * M_TOT, s6);
      atomicAdd(base + (size_t)b8 * M_TOT, s8);
    }
  }
}

// ---------------------------------------------------------------------------
// valueT[b][cv][128] hi/lo = Wv[cv,:] . pooled_x[b,:,s] + bv[cv]
// pooled_x from xpsum[b][110][512] (sums; scale applied on load). s>=110 -> 0
// ---------------------------------------------------------------------------
__global__ __launch_bounds__(256) void value_kernel(
    const float* __restrict__ Wv, const float* __restrict__ xpsum,
    const float* __restrict__ bv, u16* __restrict__ vth,
    u16* __restrict__ vtl) {
  int b = blockIdx.x >> 7, s = blockIdx.x & 127;
  int t = threadIdx.x;
  size_t o = ((size_t)(b * 256 + t)) * 128 + s;
  if (s >= S_TOT) { vth[o] = 0; vtl[o] = 0; return; }
  float scale = pool_scale(s);
  __shared__ float xs[512];
  for (int i = t; i < 512; i += 256)
    xs[i] = xpsum[((size_t)b * 110 + s) * 512 + i] * scale;
  __syncthreads();
  float accv = 0.f;
  const float* wv = Wv + (size_t)t * 512;
  for (int k = 0; k < 512; k += 4) {
    float4 w4 = *(const float4*)&wv[k];
    accv += w4.x * xs[k] + w4.y * xs[k + 1] + w4.z * xs[k + 2] + w4.w * xs[k + 3];
  }
  accv += bv[t];
  u16 h = f2bf(accv);
  vth[o] = h;
  vtl[o] = f2bf(accv - bf2f(h));
}

// ---------------------------------------------------------------------------
// keypT[b][128][256] hi/lo. SUMLAYOUT=1: from keypsum[b][110][256] (sums,
// scale applied); SUMLAYOUT=0 (fallback): from keyp[b][256][110] (means).
// s>=110 -> 0.
// ---------------------------------------------------------------------------
template <int SUMLAYOUT>
__global__ __launch_bounds__(256) void convert_key(const float* __restrict__ keyp,
                                                   u16* __restrict__ kth,
                                                   u16* __restrict__ ktl) {
  int b = blockIdx.x;
  int t = threadIdx.x;
  for (int i = t; i < 128 * 256; i += 256) {
    int s = i >> 8, c = i & 255;
    float v = 0.f;
    if (s < S_TOT) {
      if (SUMLAYOUT)
        v = keyp[((size_t)(b * 110 + s)) * 256 + c] * pool_scale(s);
      else
        v = keyp[((size_t)(b * 256 + c)) * S_TOT + s];
    }
    u16 h = f2bf(v);
    size_t o = ((size_t)(b * 128 + s)) * 256 + c;
    kth[o] = h;
    ktl[o] = f2bf(v - bf2f(h));
  }
}

// ---------------------------------------------------------------------------
// MFMA attention v2. Per block: 64 pixels, 4 waves. (unchanged)
// ---------------------------------------------------------------------------
__global__ __launch_bounds__(256) void attn_mfma(
    const u16* __restrict__ qh, const u16* __restrict__ ql,
    const u16* __restrict__ kh, const u16* __restrict__ kl,
    const u16* __restrict__ vh, const u16* __restrict__ vl,
    u16* __restrict__ aggh, u16* __restrict__ aggl) {
  __shared__ alignas(16) u16 lds[17408];
  int b = blockIdx.y, pix0 = blockIdx.x * 64;
  int t = threadIdx.x, w = t >> 6, l = t & 63;
  int fr = l & 15, q = l >> 4;

  const u16* kbase_h = kh + (size_t)b * 128 * 256;
  const u16* kbase_l = kl + (size_t)b * 128 * 256;

  f32x4 acc[8];
#pragma unroll
  for (int st = 0; st < 8; ++st) acc[st] = (f32x4){0.f, 0.f, 0.f, 0.f};

  const u16* qbh = qh + ((size_t)(b * HW + pix0 + w * 16 + fr)) * 256 + q * 8;
  const u16* qbl = ql + ((size_t)(b * HW + pix0 + w * 16 + fr)) * 256 + q * 8;

  auto stageK = [&](int ks, int buf) {
    int c0 = ks * 32;
#pragma unroll
    for (int j = 0; j < 4; ++j) {
      int i = t + j * 256;
      int half = i >> 9;
      int idx = i & 511;
      int st = idx >> 6, ll = idx & 63;
      const u16* src = (half ? kbase_l : kbase_h) +
                       (st * 16 + (ll & 15)) * 256 + c0 + (ll >> 4) * 8;
      async16(&lds[buf * 8192 + half * 4096 + idx * 8], src);
    }
  };

  stageK(0, 0);
  for (int ks = 0; ks < 8; ++ks) {
    __syncthreads();
    if (ks < 7) stageK(ks + 1, (ks + 1) & 1);
    bf16x8 ah = *(const bf16x8*)(qbh + ks * 32);
    bf16x8 al = *(const bf16x8*)(qbl + ks * 32);
    const u16* kb = &lds[(ks & 1) * 8192 + l * 8];
#pragma unroll
    for (int st = 0; st < 8; ++st) {
      bf16x8 bh = *(const bf16x8*)(kb + st * 512);
      bf16x8 bl = *(const bf16x8*)(kb + 4096 + st * 512);
      acc[st] = __builtin_amdgcn_mfma_f32_16x16x32_bf16(ah, bh, acc[st], 0, 0, 0);
      acc[st] = __builtin_amdgcn_mfma_f32_16x16x32_bf16(ah, bl, acc[st], 0, 0, 0);
      acc[st] = __builtin_amdgcn_mfma_f32_16x16x32_bf16(al, bh, acc[st], 0, 0, 0);
    }
  }

#pragma unroll
  for (int st = 0; st < 8; ++st)
#pragma unroll
    for (int r = 0; r < 4; ++r) acc[st][r] *= 0.0625f;
  if (fr >= 14) {
#pragma unroll
    for (int r = 0; r < 4; ++r) acc[6][r] = -1e30f;
  }
#pragma unroll
  for (int r = 0; r < 4; ++r) acc[7][r] = -1e30f;

#pragma unroll
  for (int r = 0; r < 4; ++r) {
    float m = -1e30f;
#pragma unroll
    for (int st = 0; st < 8; ++st) m = fmaxf(m, acc[st][r]);
    m = fmaxf(m, __shfl_xor(m, 1));
    m = fmaxf(m, __shfl_xor(m, 2));
    m = fmaxf(m, __shfl_xor(m, 4));
    m = fmaxf(m, __shfl_xor(m, 8));
    float s = 0.f;
#pragma unroll
    for (int st = 0; st < 8; ++st) {
      float e = __expf(acc[st][r] - m);
      acc[st][r] = e;
      s += e;
    }
    s += __shfl_xor(s, 1);
    s += __shfl_xor(s, 2);
    s += __shfl_xor(s, 4);
    s += __shfl_xor(s, 8);
    float inv = 1.f / s;
#pragma unroll
    for (int st = 0; st < 8; ++st) acc[st][r] *= inv;
  }

  __syncthreads();

  int prow = w * 16 + q * 4;
#pragma unroll
  for (int st = 0; st < 8; ++st) {
    int s = st * 16 + fr;
#pragma unroll
    for (int r = 0; r < 4; ++r) {
      float v = acc[st][r];
      u16 h = f2bf(v);
      lds[(prow + r) * 136 + s] = h;
      lds[8704 + (prow + r) * 136 + s] = f2bf(v - bf2f(h));
    }
  }
  __syncthreads();

  f32x4 oacc[4][4];
#pragma unroll
  for (int nt = 0; nt < 4; ++nt)
#pragma unroll
    for (int pt = 0; pt < 4; ++pt) oacc[nt][pt] = (f32x4){0.f, 0.f, 0.f, 0.f};

  const u16* vbh = vh + ((size_t)(b * 256 + w * 64 + fr)) * 128 + q * 8;
  const u16* vbl = vl + ((size_t)(b * 256 + w * 64 + fr)) * 128 + q * 8;

#pragma unroll
  for (int kc = 0; kc < 4; ++kc) {
    bf16x8 ph[4], pl[4];
#pragma unroll
    for (int pt = 0; pt < 4; ++pt) {
      ph[pt] = *(const bf16x8*)&lds[(pt * 16 + fr) * 136 + kc * 32 + q * 8];
      pl[pt] = *(const bf16x8*)&lds[8704 + (pt * 16 + fr) * 136 + kc * 32 + q * 8];
    }
#pragma unroll
    for (int nt = 0; nt < 4; ++nt) {
      bf16x8 a_h = *(const bf16x8*)(vbh + (size_t)nt * 16 * 128 + kc * 32);
      bf16x8 a_l = *(const bf16x8*)(vbl + (size_t)nt * 16 * 128 + kc * 32);
#pragma unroll
      for (int pt = 0; pt < 4; ++pt) {
        oacc[nt][pt] = __builtin_amdgcn_mfma_f32_16x16x32_bf16(a_h, ph[pt], oacc[nt][pt], 0, 0, 0);
        oacc[nt][pt] = __builtin_amdgcn_mfma_f32_16x16x32_bf16(a_h, pl[pt], oacc[nt][pt], 0, 0, 0);
        oacc[nt][pt] = __builtin_amdgcn_mfma_f32_16x16x32_bf16(a_l, ph[pt], oacc[nt][pt], 0, 0, 0);
      }
    }
  }

#pragma unroll
  for (int nt = 0; nt < 4; ++nt) {
#pragma unroll
    for (int pt = 0; pt < 4; ++pt) {
      ushort4 oh, ol;
      float v0 = oacc[nt][pt][0], v1 = oacc[nt][pt][1];
      float v2 = oacc[nt][pt][2], v3 = oacc[nt][pt][3];
      oh.x = f2bf(v0); ol.x = f2bf(v0 - bf2f(oh.x));
      oh.y = f2bf(v1); ol.y = f2bf(v1 - bf2f(oh.y));
      oh.z = f2bf(v2); ol.z = f2bf(v2 - bf2f(oh.z));
      oh.w = f2bf(v3); ol.w = f2bf(v3 - bf2f(oh.w));
      size_t o = ((size_t)(b * HW + pix0 + pt * 16 + fr)) * 256 + (w * 4 + nt) * 16 + q * 4;
      *(ushort4*)&aggh[o] = oh;
      *(ushort4*)&aggl[o] = ol;
    }
  }
}

extern "C" void kernel_launch(void* const* d_in, const int* in_sizes, int n_in,
                              void* d_out, int out_size, void* d_ws, size_t ws_size,
                              hipStream_t stream) {
  (void)in_sizes; (void)n_in; (void)out_size;
  const float* x     = (const float*)d_in[0];
  const float* Wk    = (const float*)d_in[1];
  const float* bk    = (const float*)d_in[2];
  const float* gamma = (const float*)d_in[3];
  const float* beta  = (const float*)d_in[4];
  const float* mean  = (const float*)d_in[5];
  const float* var   = (const float*)d_in[6];
  const float* Wv    = (const float*)d_in[7];
  const float* bv    = (const float*)d_in[8];
  const float* Wo    = (const float*)d_in[9];
  const float* bo    = (const float*)d_in[10];
  float* out = (float*)d_out;

  char* p = (char*)d_ws;
  float* kq = (float*)p;      p += (size_t)14745600 * 4;   // fp32 kq (fallback only)
  u16* xth = (u16*)p;         p += (size_t)29491200 * 2;   // 4*14400*512 bf16
  u16* xtl = (u16*)p;         p += (size_t)29491200 * 2;
  u16* wkh = (u16*)p;         p += 131072 * 2;
  u16* wkl = (u16*)p;         p += 131072 * 2;
  u16* woh = (u16*)p;         p += 131072 * 2;
  u16* wol = (u16*)p;         p += 131072 * 2;
  float* xpsum = (float*)p;   p += (size_t)4 * 110 * 512 * 4;  // pooled-x sums [b][110][512]
  float* keypsum = (float*)p; p += (size_t)4 * 110 * 256 * 4;  // pooled-kq sums [b][110][256]
  u16* vth = (u16*)p;         p += (size_t)4 * 256 * 128 * 2;
  u16* vtl = (u16*)p;         p += (size_t)4 * 256 * 128 * 2;
  u16* kth = (u16*)p;         p += (size_t)4 * 128 * 256 * 2;
  u16* ktl = (u16*)p;         p += (size_t)4 * 128 * 256 * 2;
  // fused kqT needs dedicated buffers (cannot alias xth/xtl: gemm_kq reads
  // those as B while writing kqT). Fallback to convert_t<256> if ws short.
  u16* kqth_f = (u16*)p;      p += (size_t)14745600 * 2;   // 4*14400*256 bf16
  u16* kqtl_f = (u16*)p;      p += (size_t)14745600 * 2;
  bool fused = ((size_t)(p - (char*)d_ws) <= ws_size);

  // aliases: xth/xtl (59MB each) are dead after gemm_kq.
  u16* aggh = xth;
  u16* aggl = xtl;
  u16* kqth = fused ? kqth_f : xth + (size_t)14745600;
  u16* kqtl = fused ? kqtl_f : xtl + (size_t)14745600;

  // zero pooled-sum accumulators (re-done every call; graph-capture safe)
  hipMemsetAsync(xpsum, 0, (size_t)4 * 110 * 512 * 4, stream);
  hipMemsetAsync(keypsum, 0, (size_t)4 * 110 * 256 * 4, stream);

  // weight splits
  convert_w<<<512, 256, 0, stream>>>(Wk, wkh, wkl, 256 * 512);
  convert_w<<<512, 256, 0, stream>>>(Wo, woh, wol, 512 * 256);
  // X -> transposed bf16 hi/lo, with fused pyramid-pool partial sums
  convert_t<512><<<dim3(225, 8, 4), 256, 0, stream>>>(x, xth, xtl, xpsum);
  // valueT = split(Wv . pooled_x + bv), s-padded
  value_kernel<<<dim3(4 * 128), 256, 0, stream>>>(Wv, xpsum, bv, vth, vtl);
  // kq GEMM: ring-pipelined, fused kqT store + fused pyramid pooling.
  // Fused path writes NO fp32 kq (C=nullptr).
  gemm_mfma<512, 256, true><<<dim3(75, 2, 4), 512, 0, stream>>>(
      wkh, wkl, xth, xtl, fused ? nullptr : kq, bk, gamma, beta, mean, var,
      fused ? kqth : (u16*)nullptr, fused ? kqtl : (u16*)nullptr,
      fused ? keypsum : (float*)nullptr);
  if (!fused) {
    convert_t<256><<<dim3(225, 4, 4), 256, 0, stream>>>(kq, kqth, kqtl, nullptr);
    pool_kernel<<<dim3(4 * 256), dim3(256), 0, stream>>>(kq, keypsum);  // old layout
    convert_key<0><<<dim3(4), dim3(256), 0, stream>>>(keypsum, kth, ktl);
  } else {
    convert_key<1><<<dim3(4), dim3(256), 0, stream>>>(keypsum, kth, ktl);
  }
  // fused MFMA attention -> agg split bf16
  attn_mfma<<<dim3(225, 4), 256, 0, stream>>>(kqth, kqtl, kth, ktl, vth, vtl,
                                              aggh, aggl);
  // out = conv_out(agg) + bo  [ring-pipelined]
  gemm_mfma<256, 512, false><<<dim3(75, 4, 4), 512, 0, stream>>>(
      woh, wol, aggh, aggl, out, bo, nullptr, nullptr, nullptr, nullptr,
      nullptr, nullptr, nullptr);
}

// Round 8
// 566.264 us; speedup vs baseline: 1.0428x; 1.0428x over previous
//
#include <hip/hip_runtime.h>
#include <cstdint>
#include <cstddef>

#define HW 14400
#define WIDTH 120
#define S_TOT 110

typedef unsigned short u16;
typedef __attribute__((ext_vector_type(8))) short bf16x8;
typedef __attribute__((ext_vector_type(4))) float f32x4;

__device__ __forceinline__ u16 f2bf(float x) {
  unsigned u = __float_as_uint(x);
  unsigned r = (u + 0x7fffu + ((u >> 16) & 1u)) >> 16;
  return (u16)r;
}
__device__ __forceinline__ float bf2f(u16 h) {
  return __uint_as_float((unsigned)h << 16);
}

__device__ __forceinline__ void async16(void* lds, const void* g) {
  __builtin_amdgcn_global_load_lds(
      (const __attribute__((address_space(1))) void*)g,
      (__attribute__((address_space(3))) void*)lds, 16, 0, 0);
}

__device__ __forceinline__ float pool_scale(int s) {
  return (s == 0) ? (1.f / 14400.f)
         : (s < 10) ? (1.f / 1600.f)
         : (s < 46) ? (1.f / 400.f)
                    : (1.f / 225.f);
}

// ---------------------------------------------------------------------------
// Pyramid pooling (means): in [nplanes][14400] -> out [nplanes][110]
// Coalesced column-band sums, then 5-wide windows, then pyramid bins.
// ---------------------------------------------------------------------------
__global__ __launch_bounds__(256) void pool_kernel(const float* __restrict__ in,
                                                   float* __restrict__ outp) {
  __shared__ float colsum[2880];
  __shared__ float part[576];
  const float* plane = in + (size_t)blockIdx.x * HW;
  int t = threadIdx.x;
  for (int i = t; i < 2880; i += 256) {
    int by = i / 120, x = i - by * 120;
    const float* p0 = plane + (by * 5) * WIDTH + x;
    colsum[i] = p0[0] + p0[WIDTH] + p0[2 * WIDTH] + p0[3 * WIDTH] + p0[4 * WIDTH];
  }
  __syncthreads();
  for (int bb = t; bb < 576; bb += 256) {
    int by = bb / 24, bx = bb - by * 24;
    const float* c = &colsum[by * 120 + bx * 5];
    part[bb] = c[0] + c[1] + c[2] + c[3] + c[4];
  }
  __syncthreads();
  if (t < S_TOT) {
    float s = 0.f;
    if (t == 0) {
      for (int i = 0; i < 576; ++i) s += part[i];
      s *= (1.f / 14400.f);
    } else if (t < 10) {
      int idx = t - 1, i = idx / 3, j = idx % 3;
      for (int a = 0; a < 8; ++a)
        for (int c = 0; c < 8; ++c) s += part[(i * 8 + a) * 24 + (j * 8 + c)];
      s *= (1.f / 1600.f);
    } else if (t < 46) {
      int idx = t - 10, i = idx / 6, j = idx % 6;
      for (int a = 0; a < 4; ++a)
        for (int c = 0; c < 4; ++c) s += part[(i * 4 + a) * 24 + (j * 4 + c)];
      s *= (1.f / 400.f);
    } else {
      int idx = t - 46, i = idx / 8, j = idx % 8;
      for (int a = 0; a < 3; ++a)
        for (int c = 0; c < 3; ++c) s += part[(i * 3 + a) * 24 + (j * 3 + c)];
      s *= (1.f / 225.f);
    }
    outp[(size_t)blockIdx.x * S_TOT + t] = s;
  }
}

// ---------------------------------------------------------------------------
// Split fp32 weight -> bf16 hi/lo (elementwise)
// ---------------------------------------------------------------------------
__global__ __launch_bounds__(256) void convert_w(const float* __restrict__ in,
                                                 u16* __restrict__ hi,
                                                 u16* __restrict__ lo, int n) {
  int i = blockIdx.x * 256 + threadIdx.x;
  if (i < n) {
    float v = in[i];
    u16 h = f2bf(v);
    hi[i] = h;
    lo[i] = f2bf(v - bf2f(h));
  }
}

// ---------------------------------------------------------------------------
// X [b][CIN][14400] fp32 -> XT hi/lo [b][14400][CIN] bf16 (transpose + split)
// ---------------------------------------------------------------------------
template <int CIN>
__global__ __launch_bounds__(256) void convert_t(const float* __restrict__ X,
                                                 u16* __restrict__ xth,
                                                 u16* __restrict__ xtl) {
  __shared__ float ls[64][65];
  int b = blockIdx.z;
  int n0 = blockIdx.x * 64, k0 = blockIdx.y * 64;
  int t = threadIdx.x;
  int rt = t >> 4, c4 = (t & 15) * 4;
#pragma unroll
  for (int rr = 0; rr < 4; ++rr) {
    int kk = rr * 16 + rt;
    float4 v = *(const float4*)&X[((size_t)(b * CIN + k0 + kk)) * HW + n0 + c4];
    ls[kk][c4] = v.x; ls[kk][c4 + 1] = v.y; ls[kk][c4 + 2] = v.z; ls[kk][c4 + 3] = v.w;
  }
  __syncthreads();
#pragma unroll
  for (int rr = 0; rr < 4; ++rr) {
    int nn = rr * 16 + rt;
    float v0 = ls[c4 + 0][nn], v1 = ls[c4 + 1][nn], v2 = ls[c4 + 2][nn], v3 = ls[c4 + 3][nn];
    ushort4 oh, ol;
    oh.x = f2bf(v0); ol.x = f2bf(v0 - bf2f(oh.x));
    oh.y = f2bf(v1); ol.y = f2bf(v1 - bf2f(oh.y));
    oh.z = f2bf(v2); ol.z = f2bf(v2 - bf2f(oh.z));
    oh.w = f2bf(v3); ol.w = f2bf(v3 - bf2f(oh.w));
    size_t idx = ((size_t)(b * HW + n0 + nn)) * CIN + k0 + c4;
    *(ushort4*)&xth[idx] = oh;
    *(ushort4*)&xtl[idx] = ol;
  }
}

// ---------------------------------------------------------------------------
// Split-bf16 MFMA GEMM v8:  epi( sum_k A[m][k]*B[b][n][k] )
//  Main loop = harness-verified v5/v6 (3-slot ring, counted vmcnt(5),
//  setprio). Epilogue: optional C store (C==nullptr in the fused kq path)
//  + optional split-bf16 LDS transpose -> coalesced kqT stores (v6-verified).
//  NO fused pooling (r7 showed it VALU-serializes the tail).
// ---------------------------------------------------------------------------
template <int K, int M_TOT, bool BNRELU>
__global__ __launch_bounds__(512, 2) void gemm_mfma(
    const u16* __restrict__ Ah, const u16* __restrict__ Al,
    const u16* __restrict__ Bh, const u16* __restrict__ Bl,
    float* __restrict__ C,
    const float* __restrict__ p0, const float* __restrict__ p1,
    const float* __restrict__ p2, const float* __restrict__ p3,
    const float* __restrict__ p4,
    u16* __restrict__ Th, u16* __restrict__ Tl) {
  constexpr int NSTEP = K / 32;
  // unified: ring sA = smem[0..24576), ring sB = smem[24576..61440)
  // epilogue transpose: hi = smem[0..26112), lo = smem[26112..52224)
  __shared__ alignas(16) u16 smem[61440];

  int t = threadIdx.x, w = t >> 6, l = t & 63;
  int wm = w >> 2, wn = w & 3;
  int b = blockIdx.z;
  int n0 = blockIdx.x * 192;
  int m0 = blockIdx.y * 128;

  int fr = l & 15, fkc = l >> 4;
  const size_t bOff = (size_t)b * HW;

  auto stage = [&](int ks, int slot) {
    int k0 = ks * 32;
#pragma unroll
    for (int c = 0; c < 5; ++c) {
      int i = w * 5 + c;
      const u16* g;
      u16* d;
      if (i < 8) {
        g = Ah + (size_t)(m0 + i * 16 + fr) * K + k0 + fkc * 8;
        d = &smem[slot * 8192 + i * 512];
      } else if (i < 16) {
        g = Al + (size_t)(m0 + (i - 8) * 16 + fr) * K + k0 + fkc * 8;
        d = &smem[slot * 8192 + i * 512];
      } else if (i < 28) {
        g = Bh + (bOff + n0 + (i - 16) * 16 + fr) * (size_t)K + k0 + fkc * 8;
        d = &smem[24576 + slot * 12288 + (i - 16) * 512];
      } else {
        g = Bl + (bOff + n0 + (i - 28) * 16 + fr) * (size_t)K + k0 + fkc * 8;
        d = &smem[24576 + slot * 12288 + (i - 16) * 512];
      }
      async16(d, g);
    }
  };

  f32x4 acc[4][3];
#pragma unroll
  for (int i = 0; i < 4; ++i)
#pragma unroll
    for (int j = 0; j < 3; ++j) acc[i][j] = (f32x4){0.f, 0.f, 0.f, 0.f};

  stage(0, 0);
  stage(1, 1);

  for (int ks = 0; ks < NSTEP; ++ks) {
    if (ks + 1 < NSTEP)
      asm volatile("s_waitcnt vmcnt(5)" ::: "memory");
    else
      asm volatile("s_waitcnt vmcnt(0)" ::: "memory");
    __builtin_amdgcn_s_barrier();
    __builtin_amdgcn_sched_barrier(0);

    if (ks + 2 < NSTEP) stage(ks + 2, (ks + 2) % 3);

    int cur = ks % 3;
    bf16x8 bh[3], bl[3];
#pragma unroll
    for (int nt = 0; nt < 3; ++nt) {
      bh[nt] = *(const bf16x8*)&smem[24576 + cur * 12288 + (wn * 3 + nt) * 512 + l * 8];
      bl[nt] = *(const bf16x8*)&smem[24576 + cur * 12288 + (12 + wn * 3 + nt) * 512 + l * 8];
    }
    bf16x8 ah[4], al[4];
#pragma unroll
    for (int mt = 0; mt < 4; ++mt) {
      ah[mt] = *(const bf16x8*)&smem[cur * 8192 + (wm * 4 + mt) * 512 + l * 8];
      al[mt] = *(const bf16x8*)&smem[cur * 8192 + (8 + wm * 4 + mt) * 512 + l * 8];
    }
    __builtin_amdgcn_s_setprio(1);
#pragma unroll
    for (int mt = 0; mt < 4; ++mt)
#pragma unroll
      for (int nt = 0; nt < 3; ++nt) {
        acc[mt][nt] = __builtin_amdgcn_mfma_f32_16x16x32_bf16(ah[mt], bh[nt], acc[mt][nt], 0, 0, 0);
        acc[mt][nt] = __builtin_amdgcn_mfma_f32_16x16x32_bf16(ah[mt], bl[nt], acc[mt][nt], 0, 0, 0);
        acc[mt][nt] = __builtin_amdgcn_mfma_f32_16x16x32_bf16(al[mt], bh[nt], acc[mt][nt], 0, 0, 0);
      }
    __builtin_amdgcn_s_setprio(0);
  }

  __syncthreads();  // all ring LDS reads done before epilogue reuses smem

  int q4 = (l >> 4) * 4;
#pragma unroll
  for (int mt = 0; mt < 4; ++mt) {
    int mb = m0 + (wm * 4 + mt) * 16 + q4;
    float iv[4], ad[4];
    if (BNRELU) {
      float4 g0 = *(const float4*)&p0[mb];
      float4 g1 = *(const float4*)&p1[mb];
      float4 g2 = *(const float4*)&p2[mb];
      float4 g3 = *(const float4*)&p3[mb];
      float4 g4 = *(const float4*)&p4[mb];
      iv[0] = g1.x * rsqrtf(g4.x + 1e-5f);
      iv[1] = g1.y * rsqrtf(g4.y + 1e-5f);
      iv[2] = g1.z * rsqrtf(g4.z + 1e-5f);
      iv[3] = g1.w * rsqrtf(g4.w + 1e-5f);
      ad[0] = (g0.x - g3.x) * iv[0] + g2.x;
      ad[1] = (g0.y - g3.y) * iv[1] + g2.y;
      ad[2] = (g0.z - g3.z) * iv[2] + g2.z;
      ad[3] = (g0.w - g3.w) * iv[3] + g2.w;
    } else {
      float4 g0 = *(const float4*)&p0[mb];
      ad[0] = g0.x; ad[1] = g0.y; ad[2] = g0.z; ad[3] = g0.w;
    }
#pragma unroll
    for (int nt = 0; nt < 3; ++nt) {
      int n = n0 + (wn * 3 + nt) * 16 + fr;
      float v[4];
#pragma unroll
      for (int r = 0; r < 4; ++r) {
        float x = acc[mt][nt][r];
        v[r] = BNRELU ? fmaxf(x * iv[r] + ad[r], 0.f) : x + ad[r];
        if (C) C[((size_t)(b * M_TOT) + mb + r) * HW + n] = v[r];
      }
      if (BNRELU && Th) {
        ushort4 hh, ll;
        hh.x = f2bf(v[0]); ll.x = f2bf(v[0] - bf2f(hh.x));
        hh.y = f2bf(v[1]); ll.y = f2bf(v[1] - bf2f(hh.y));
        hh.z = f2bf(v[2]); ll.z = f2bf(v[2] - bf2f(hh.z));
        hh.w = f2bf(v[3]); ll.w = f2bf(v[3] - bf2f(hh.w));
        int nl = (wn * 3 + nt) * 16 + fr;
        int ml = (wm * 4 + mt) * 16 + q4;
        *(ushort4*)&smem[nl * 136 + ml] = hh;
        *(ushort4*)&smem[26112 + nl * 136 + ml] = ll;
      }
    }
  }
  if (BNRELU && Th) {
    __syncthreads();
    // coalesced kqT stores: row = pixel (n), 128 u16 of channels
#pragma unroll
    for (int it = 0; it < 6; ++it) {
      int row = it * 32 + (t >> 4);
      int c8 = (t & 15) * 8;
      size_t go = (bOff + n0 + row) * (size_t)M_TOT + m0 + c8;
      *(bf16x8*)&Th[go] = *(const bf16x8*)&smem[row * 136 + c8];
      *(bf16x8*)&Tl[go] = *(const bf16x8*)&smem[26112 + row * 136 + c8];
    }
  }
}

// ---------------------------------------------------------------------------
// Pyramid-pool kq from the transposed split-bf16 buffers:
// kqth/kqtl [b][14400][256] -> keypsum[b][110][256] (SUMS; atomicAdd).
// Grid (4 col-quarters, 24 row-bands, 4 b); thread = channel. Each 5-row
// band lies within one row-bin at every pyramid level (5 | 15,20,40).
// Running col-bin accumulation, flush-on-change: ~7 atomics/thread.
// ---------------------------------------------------------------------------
__global__ __launch_bounds__(256) void pool_kqt(const u16* __restrict__ kqth,
                                                const u16* __restrict__ kqtl,
                                                float* __restrict__ keypsum) {
  int cq = blockIdx.x, band = blockIdx.y, b = blockIdx.z;
  int t = threadIdx.x;
  int row0 = band * 5, col0 = cq * 30;
  int r3 = row0 / 40, r6 = row0 / 20, r8 = row0 / 15;
  float* base = keypsum + (size_t)b * 110 * 256 + t;
  float s1 = 0.f, s3 = 0.f, s6 = 0.f, s8 = 0.f;
  int b3 = -1, b6 = -1, b8 = -1;
  for (int cc = 0; cc < 30; ++cc) {
    int col = col0 + cc;
    float v = 0.f;
#pragma unroll
    for (int r = 0; r < 5; ++r) {
      size_t o = ((size_t)(b * HW + (row0 + r) * 120 + col)) * 256 + t;
      v += bf2f(kqth[o]) + bf2f(kqtl[o]);
    }
    int i3 = 1 + r3 * 3 + col / 40;
    int i6 = 10 + r6 * 6 + col / 20;
    int i8 = 46 + r8 * 8 + col / 15;
    s1 += v;
    if (i3 != b3) { if (b3 >= 0) atomicAdd(base + (size_t)b3 * 256, s3); s3 = 0.f; b3 = i3; }
    s3 += v;
    if (i6 != b6) { if (b6 >= 0) atomicAdd(base + (size_t)b6 * 256, s6); s6 = 0.f; b6 = i6; }
    s6 += v;
    if (i8 != b8) { if (b8 >= 0) atomicAdd(base + (size_t)b8 * 256, s8); s8 = 0.f; b8 = i8; }
    s8 += v;
  }
  atomicAdd(base, s1);
  atomicAdd(base + (size_t)b3 * 256, s3);
  atomicAdd(base + (size_t)b6 * 256, s6);
  atomicAdd(base + (size_t)b8 * 256, s8);
}

// ---------------------------------------------------------------------------
// valueT[b][cv][128] hi/lo = Wv[cv,:] . xp[b,:,s] + bv[cv]  (s>=110 -> 0)
// xp layout [b*512+ch][110] (means, from pool_kernel)
// ---------------------------------------------------------------------------
__global__ __launch_bounds__(256) void value_kernel(
    const float* __restrict__ Wv, const float* __restrict__ xp,
    const float* __restrict__ bv, u16* __restrict__ vth,
    u16* __restrict__ vtl) {
  int b = blockIdx.x >> 7, s = blockIdx.x & 127;
  int t = threadIdx.x;
  size_t o = ((size_t)(b * 256 + t)) * 128 + s;
  if (s >= S_TOT) { vth[o] = 0; vtl[o] = 0; return; }
  __shared__ float xs[512];
  for (int i = t; i < 512; i += 256) xs[i] = xp[((size_t)b * 512 + i) * S_TOT + s];
  __syncthreads();
  float accv = 0.f;
  const float* wv = Wv + (size_t)t * 512;
  for (int k = 0; k < 512; k += 4) {
    float4 w4 = *(const float4*)&wv[k];
    accv += w4.x * xs[k] + w4.y * xs[k + 1] + w4.z * xs[k + 2] + w4.w * xs[k + 3];
  }
  accv += bv[t];
  u16 h = f2bf(accv);
  vth[o] = h;
  vtl[o] = f2bf(accv - bf2f(h));
}

// ---------------------------------------------------------------------------
// keypT[b][128][256] hi/lo. SUMLAYOUT=1: from keypsum[b][110][256] (sums,
// pool_scale applied); SUMLAYOUT=0 (fallback): from keyp[b][256][110] (means)
// s>=110 -> 0.
// ---------------------------------------------------------------------------
template <int SUMLAYOUT>
__global__ __launch_bounds__(256) void convert_key(const float* __restrict__ keyp,
                                                   u16* __restrict__ kth,
                                                   u16* __restrict__ ktl) {
  int b = blockIdx.x;
  int t = threadIdx.x;
  for (int i = t; i < 128 * 256; i += 256) {
    int s = i >> 8, c = i & 255;
    float v = 0.f;
    if (s < S_TOT) {
      if (SUMLAYOUT)
        v = keyp[((size_t)(b * 110 + s)) * 256 + c] * pool_scale(s);
      else
        v = keyp[((size_t)(b * 256 + c)) * S_TOT + s];
    }
    u16 h = f2bf(v);
    size_t o = ((size_t)(b * 128 + s)) * 256 + c;
    kth[o] = h;
    ktl[o] = f2bf(v - bf2f(h));
  }
}

// ---------------------------------------------------------------------------
// MFMA attention v2. Per block: 64 pixels, 4 waves. (unchanged)
// ---------------------------------------------------------------------------
__global__ __launch_bounds__(256) void attn_mfma(
    const u16* __restrict__ qh, const u16* __restrict__ ql,
    const u16* __restrict__ kh, const u16* __restrict__ kl,
    const u16* __restrict__ vh, const u16* __restrict__ vl,
    u16* __restrict__ aggh, u16* __restrict__ aggl) {
  __shared__ alignas(16) u16 lds[17408];
  int b = blockIdx.y, pix0 = blockIdx.x * 64;
  int t = threadIdx.x, w = t >> 6, l = t & 63;
  int fr = l & 15, q = l >> 4;

  const u16* kbase_h = kh + (size_t)b * 128 * 256;
  const u16* kbase_l = kl + (size_t)b * 128 * 256;

  f32x4 acc[8];
#pragma unroll
  for (int st = 0; st < 8; ++st) acc[st] = (f32x4){0.f, 0.f, 0.f, 0.f};

  const u16* qbh = qh + ((size_t)(b * HW + pix0 + w * 16 + fr)) * 256 + q * 8;
  const u16* qbl = ql + ((size_t)(b * HW + pix0 + w * 16 + fr)) * 256 + q * 8;

  auto stageK = [&](int ks, int buf) {
    int c0 = ks * 32;
#pragma unroll
    for (int j = 0; j < 4; ++j) {
      int i = t + j * 256;
      int half = i >> 9;
      int idx = i & 511;
      int st = idx >> 6, ll = idx & 63;
      const u16* src = (half ? kbase_l : kbase_h) +
                       (st * 16 + (ll & 15)) * 256 + c0 + (ll >> 4) * 8;
      async16(&lds[buf * 8192 + half * 4096 + idx * 8], src);
    }
  };

  stageK(0, 0);
  for (int ks = 0; ks < 8; ++ks) {
    __syncthreads();
    if (ks < 7) stageK(ks + 1, (ks + 1) & 1);
    bf16x8 ah = *(const bf16x8*)(qbh + ks * 32);
    bf16x8 al = *(const bf16x8*)(qbl + ks * 32);
    const u16* kb = &lds[(ks & 1) * 8192 + l * 8];
#pragma unroll
    for (int st = 0; st < 8; ++st) {
      bf16x8 bh = *(const bf16x8*)(kb + st * 512);
      bf16x8 bl = *(const bf16x8*)(kb + 4096 + st * 512);
      acc[st] = __builtin_amdgcn_mfma_f32_16x16x32_bf16(ah, bh, acc[st], 0, 0, 0);
      acc[st] = __builtin_amdgcn_mfma_f32_16x16x32_bf16(ah, bl, acc[st], 0, 0, 0);
      acc[st] = __builtin_amdgcn_mfma_f32_16x16x32_bf16(al, bh, acc[st], 0, 0, 0);
    }
  }

#pragma unroll
  for (int st = 0; st < 8; ++st)
#pragma unroll
    for (int r = 0; r < 4; ++r) acc[st][r] *= 0.0625f;
  if (fr >= 14) {
#pragma unroll
    for (int r = 0; r < 4; ++r) acc[6][r] = -1e30f;
  }
#pragma unroll
  for (int r = 0; r < 4; ++r) acc[7][r] = -1e30f;

#pragma unroll
  for (int r = 0; r < 4; ++r) {
    float m = -1e30f;
#pragma unroll
    for (int st = 0; st < 8; ++st) m = fmaxf(m, acc[st][r]);
    m = fmaxf(m, __shfl_xor(m, 1));
    m = fmaxf(m, __shfl_xor(m, 2));
    m = fmaxf(m, __shfl_xor(m, 4));
    m = fmaxf(m, __shfl_xor(m, 8));
    float s = 0.f;
#pragma unroll
    for (int st = 0; st < 8; ++st) {
      float e = __expf(acc[st][r] - m);
      acc[st][r] = e;
      s += e;
    }
    s += __shfl_xor(s, 1);
    s += __shfl_xor(s, 2);
    s += __shfl_xor(s, 4);
    s += __shfl_xor(s, 8);
    float inv = 1.f / s;
#pragma unroll
    for (int st = 0; st < 8; ++st) acc[st][r] *= inv;
  }

  __syncthreads();

  int prow = w * 16 + q * 4;
#pragma unroll
  for (int st = 0; st < 8; ++st) {
    int s = st * 16 + fr;
#pragma unroll
    for (int r = 0; r < 4; ++r) {
      float v = acc[st][r];
      u16 h = f2bf(v);
      lds[(prow + r) * 136 + s] = h;
      lds[8704 + (prow + r) * 136 + s] = f2bf(v - bf2f(h));
    }
  }
  __syncthreads();

  f32x4 oacc[4][4];
#pragma unroll
  for (int nt = 0; nt < 4; ++nt)
#pragma unroll
    for (int pt = 0; pt < 4; ++pt) oacc[nt][pt] = (f32x4){0.f, 0.f, 0.f, 0.f};

  const u16* vbh = vh + ((size_t)(b * 256 + w * 64 + fr)) * 128 + q * 8;
  const u16* vbl = vl + ((size_t)(b * 256 + w * 64 + fr)) * 128 + q * 8;

#pragma unroll
  for (int kc = 0; kc < 4; ++kc) {
    bf16x8 ph[4], pl[4];
#pragma unroll
    for (int pt = 0; pt < 4; ++pt) {
      ph[pt] = *(const bf16x8*)&lds[(pt * 16 + fr) * 136 + kc * 32 + q * 8];
      pl[pt] = *(const bf16x8*)&lds[8704 + (pt * 16 + fr) * 136 + kc * 32 + q * 8];
    }
#pragma unroll
    for (int nt = 0; nt < 4; ++nt) {
      bf16x8 a_h = *(const bf16x8*)(vbh + (size_t)nt * 16 * 128 + kc * 32);
      bf16x8 a_l = *(const bf16x8*)(vbl + (size_t)nt * 16 * 128 + kc * 32);
#pragma unroll
      for (int pt = 0; pt < 4; ++pt) {
        oacc[nt][pt] = __builtin_amdgcn_mfma_f32_16x16x32_bf16(a_h, ph[pt], oacc[nt][pt], 0, 0, 0);
        oacc[nt][pt] = __builtin_amdgcn_mfma_f32_16x16x32_bf16(a_h, pl[pt], oacc[nt][pt], 0, 0, 0);
        oacc[nt][pt] = __builtin_amdgcn_mfma_f32_16x16x32_bf16(a_l, ph[pt], oacc[nt][pt], 0, 0, 0);
      }
    }
  }

#pragma unroll
  for (int nt = 0; nt < 4; ++nt) {
#pragma unroll
    for (int pt = 0; pt < 4; ++pt) {
      ushort4 oh, ol;
      float v0 = oacc[nt][pt][0], v1 = oacc[nt][pt][1];
      float v2 = oacc[nt][pt][2], v3 = oacc[nt][pt][3];
      oh.x = f2bf(v0); ol.x = f2bf(v0 - bf2f(oh.x));
      oh.y = f2bf(v1); ol.y = f2bf(v1 - bf2f(oh.y));
      oh.z = f2bf(v2); ol.z = f2bf(v2 - bf2f(oh.z));
      oh.w = f2bf(v3); ol.w = f2bf(v3 - bf2f(oh.w));
      size_t o = ((size_t)(b * HW + pix0 + pt * 16 + fr)) * 256 + (w * 4 + nt) * 16 + q * 4;
      *(ushort4*)&aggh[o] = oh;
      *(ushort4*)&aggl[o] = ol;
    }
  }
}

extern "C" void kernel_launch(void* const* d_in, const int* in_sizes, int n_in,
                              void* d_out, int out_size, void* d_ws, size_t ws_size,
                              hipStream_t stream) {
  (void)in_sizes; (void)n_in; (void)out_size;
  const float* x     = (const float*)d_in[0];
  const float* Wk    = (const float*)d_in[1];
  const float* bk    = (const float*)d_in[2];
  const float* gamma = (const float*)d_in[3];
  const float* beta  = (const float*)d_in[4];
  const float* mean  = (const float*)d_in[5];
  const float* var   = (const float*)d_in[6];
  const float* Wv    = (const float*)d_in[7];
  const float* bv    = (const float*)d_in[8];
  const float* Wo    = (const float*)d_in[9];
  const float* bo    = (const float*)d_in[10];
  float* out = (float*)d_out;

  char* p = (char*)d_ws;
  float* kq = (float*)p;      p += (size_t)14745600 * 4;   // fp32 kq (fallback only)
  u16* xth = (u16*)p;         p += (size_t)29491200 * 2;   // 4*14400*512 bf16
  u16* xtl = (u16*)p;         p += (size_t)29491200 * 2;
  u16* wkh = (u16*)p;         p += 131072 * 2;
  u16* wkl = (u16*)p;         p += 131072 * 2;
  u16* woh = (u16*)p;         p += 131072 * 2;
  u16* wol = (u16*)p;         p += 131072 * 2;
  float* xp = (float*)p;      p += (size_t)4 * 512 * 110 * 4;   // pooled-x means
  float* keypsum = (float*)p; p += (size_t)4 * 110 * 256 * 4;   // pooled-kq sums
  u16* vth = (u16*)p;         p += (size_t)4 * 256 * 128 * 2;
  u16* vtl = (u16*)p;         p += (size_t)4 * 256 * 128 * 2;
  u16* kth = (u16*)p;         p += (size_t)4 * 128 * 256 * 2;
  u16* ktl = (u16*)p;         p += (size_t)4 * 128 * 256 * 2;
  // fused kqT needs dedicated buffers (cannot alias xth/xtl: gemm_kq reads
  // those as B while writing kqT). Fallback to convert_t<256> if ws short.
  u16* kqth_f = (u16*)p;      p += (size_t)14745600 * 2;   // 4*14400*256 bf16
  u16* kqtl_f = (u16*)p;      p += (size_t)14745600 * 2;
  bool fused = ((size_t)(p - (char*)d_ws) <= ws_size);

  // aliases: xth/xtl (59MB each) are dead after gemm_kq.
  u16* aggh = xth;
  u16* aggl = xtl;
  u16* kqth = fused ? kqth_f : xth + (size_t)14745600;
  u16* kqtl = fused ? kqtl_f : xtl + (size_t)14745600;

  if (fused)
    hipMemsetAsync(keypsum, 0, (size_t)4 * 110 * 256 * 4, stream);

  // weight splits
  convert_w<<<512, 256, 0, stream>>>(Wk, wkh, wkl, 256 * 512);
  convert_w<<<512, 256, 0, stream>>>(Wo, woh, wol, 512 * 256);
  // X -> transposed bf16 hi/lo
  convert_t<512><<<dim3(225, 8, 4), 256, 0, stream>>>(x, xth, xtl);
  // pyramid-pool x (pooling commutes with 1x1 conv for value)
  pool_kernel<<<dim3(4 * 512), dim3(256), 0, stream>>>(x, xp);
  // valueT = split(conv_v(pooled x) + bv), s-padded
  value_kernel<<<dim3(4 * 128), 256, 0, stream>>>(Wv, xp, bv, vth, vtl);
  // kq GEMM: ring-pipelined, fused coalesced kqT store; fp32 kq NOT written
  // in the fused path (C=nullptr).
  gemm_mfma<512, 256, true><<<dim3(75, 2, 4), 512, 0, stream>>>(
      wkh, wkl, xth, xtl, fused ? nullptr : kq, bk, gamma, beta, mean, var,
      fused ? kqth : (u16*)nullptr, fused ? kqtl : (u16*)nullptr);
  if (fused) {
    // key pooling directly from kqT split-bf16 (hi+lo, err <= 2^-18)
    pool_kqt<<<dim3(4, 24, 4), 256, 0, stream>>>(kqth, kqtl, keypsum);
    convert_key<1><<<dim3(4), dim3(256), 0, stream>>>(keypsum, kth, ktl);
  } else {
    convert_t<256><<<dim3(225, 4, 4), 256, 0, stream>>>(kq, kqth, kqtl);
    pool_kernel<<<dim3(4 * 256), dim3(256), 0, stream>>>(kq, keypsum);
    convert_key<0><<<dim3(4), dim3(256), 0, stream>>>(keypsum, kth, ktl);
  }
  // fused MFMA attention -> agg split bf16
  attn_mfma<<<dim3(225, 4), 256, 0, stream>>>(kqth, kqtl, kth, ktl, vth, vtl,
                                              aggh, aggl);
  // out = conv_out(agg) + bo  [ring-pipelined]
  gemm_mfma<256, 512, false><<<dim3(75, 4, 4), 512, 0, stream>>>(
      woh, wol, aggh, aggl, out, bo, nullptr, nullptr, nullptr, nullptr,
      nullptr, nullptr);
}

// Round 9
// 524.223 us; speedup vs baseline: 1.1264x; 1.0802x over previous
//
#include <hip/hip_runtime.h>
#include <cstdint>
#include <cstddef>

#define HW 14400
#define WIDTH 120
#define S_TOT 110

typedef unsigned short u16;
typedef __attribute__((ext_vector_type(8))) short bf16x8;
typedef __attribute__((ext_vector_type(4))) float f32x4;

__device__ __forceinline__ u16 f2bf(float x) {
  unsigned u = __float_as_uint(x);
  unsigned r = (u + 0x7fffu + ((u >> 16) & 1u)) >> 16;
  return (u16)r;
}
__device__ __forceinline__ float bf2f(u16 h) {
  return __uint_as_float((unsigned)h << 16);
}

__device__ __forceinline__ void async16(void* lds, const void* g) {
  __builtin_amdgcn_global_load_lds(
      (const __attribute__((address_space(1))) void*)g,
      (__attribute__((address_space(3))) void*)lds, 16, 0, 0);
}

__device__ __forceinline__ float pool_scale(int s) {
  return (s == 0) ? (1.f / 14400.f)
         : (s < 10) ? (1.f / 1600.f)
         : (s < 46) ? (1.f / 400.f)
                    : (1.f / 225.f);
}

// ---------------------------------------------------------------------------
// Pyramid pooling (means): in [nplanes][14400] -> out [nplanes][110]
// ---------------------------------------------------------------------------
__global__ __launch_bounds__(256) void pool_kernel(const float* __restrict__ in,
                                                   float* __restrict__ outp) {
  __shared__ float colsum[2880];
  __shared__ float part[576];
  const float* plane = in + (size_t)blockIdx.x * HW;
  int t = threadIdx.x;
  for (int i = t; i < 2880; i += 256) {
    int by = i / 120, x = i - by * 120;
    const float* p0 = plane + (by * 5) * WIDTH + x;
    colsum[i] = p0[0] + p0[WIDTH] + p0[2 * WIDTH] + p0[3 * WIDTH] + p0[4 * WIDTH];
  }
  __syncthreads();
  for (int bb = t; bb < 576; bb += 256) {
    int by = bb / 24, bx = bb - by * 24;
    const float* c = &colsum[by * 120 + bx * 5];
    part[bb] = c[0] + c[1] + c[2] + c[3] + c[4];
  }
  __syncthreads();
  if (t < S_TOT) {
    float s = 0.f;
    if (t == 0) {
      for (int i = 0; i < 576; ++i) s += part[i];
      s *= (1.f / 14400.f);
    } else if (t < 10) {
      int idx = t - 1, i = idx / 3, j = idx % 3;
      for (int a = 0; a < 8; ++a)
        for (int c = 0; c < 8; ++c) s += part[(i * 8 + a) * 24 + (j * 8 + c)];
      s *= (1.f / 1600.f);
    } else if (t < 46) {
      int idx = t - 10, i = idx / 6, j = idx % 6;
      for (int a = 0; a < 4; ++a)
        for (int c = 0; c < 4; ++c) s += part[(i * 4 + a) * 24 + (j * 4 + c)];
      s *= (1.f / 400.f);
    } else {
      int idx = t - 46, i = idx / 8, j = idx % 8;
      for (int a = 0; a < 3; ++a)
        for (int c = 0; c < 3; ++c) s += part[(i * 3 + a) * 24 + (j * 3 + c)];
      s *= (1.f / 225.f);
    }
    outp[(size_t)blockIdx.x * S_TOT + t] = s;
  }
}

// ---------------------------------------------------------------------------
// Split fp32 weight -> bf16 hi/lo (elementwise)
// ---------------------------------------------------------------------------
__global__ __launch_bounds__(256) void convert_w(const float* __restrict__ in,
                                                 u16* __restrict__ hi,
                                                 u16* __restrict__ lo, int n) {
  int i = blockIdx.x * 256 + threadIdx.x;
  if (i < n) {
    float v = in[i];
    u16 h = f2bf(v);
    hi[i] = h;
    lo[i] = f2bf(v - bf2f(h));
  }
}

// ---------------------------------------------------------------------------
// X [b][CIN][14400] fp32 -> XT hi/lo [b][14400][CIN] bf16 (fallback only)
// ---------------------------------------------------------------------------
template <int CIN>
__global__ __launch_bounds__(256) void convert_t(const float* __restrict__ X,
                                                 u16* __restrict__ xth,
                                                 u16* __restrict__ xtl) {
  __shared__ float ls[64][65];
  int b = blockIdx.z;
  int n0 = blockIdx.x * 64, k0 = blockIdx.y * 64;
  int t = threadIdx.x;
  int rt = t >> 4, c4 = (t & 15) * 4;
#pragma unroll
  for (int rr = 0; rr < 4; ++rr) {
    int kk = rr * 16 + rt;
    float4 v = *(const float4*)&X[((size_t)(b * CIN + k0 + kk)) * HW + n0 + c4];
    ls[kk][c4] = v.x; ls[kk][c4 + 1] = v.y; ls[kk][c4 + 2] = v.z; ls[kk][c4 + 3] = v.w;
  }
  __syncthreads();
#pragma unroll
  for (int rr = 0; rr < 4; ++rr) {
    int nn = rr * 16 + rt;
    float v0 = ls[c4 + 0][nn], v1 = ls[c4 + 1][nn], v2 = ls[c4 + 2][nn], v3 = ls[c4 + 3][nn];
    ushort4 oh, ol;
    oh.x = f2bf(v0); ol.x = f2bf(v0 - bf2f(oh.x));
    oh.y = f2bf(v1); ol.y = f2bf(v1 - bf2f(oh.y));
    oh.z = f2bf(v2); ol.z = f2bf(v2 - bf2f(oh.z));
    oh.w = f2bf(v3); ol.w = f2bf(v3 - bf2f(oh.w));
    size_t idx = ((size_t)(b * HW + n0 + nn)) * CIN + k0 + c4;
    *(ushort4*)&xth[idx] = oh;
    *(ushort4*)&xtl[idx] = ol;
  }
}

// ---------------------------------------------------------------------------
// Split-bf16 MFMA GEMM v8 (r8-verified; used for gemm_out + fallback kq):
// 3-slot ring, counted vmcnt(5), setprio; optional C store; optional fused
// kqT transpose epilogue.
// ---------------------------------------------------------------------------
template <int K, int M_TOT, bool BNRELU>
__global__ __launch_bounds__(512, 2) void gemm_mfma(
    const u16* __restrict__ Ah, const u16* __restrict__ Al,
    const u16* __restrict__ Bh, const u16* __restrict__ Bl,
    float* __restrict__ C,
    const float* __restrict__ p0, const float* __restrict__ p1,
    const float* __restrict__ p2, const float* __restrict__ p3,
    const float* __restrict__ p4,
    u16* __restrict__ Th, u16* __restrict__ Tl) {
  constexpr int NSTEP = K / 32;
  __shared__ alignas(16) u16 smem[61440];

  int t = threadIdx.x, w = t >> 6, l = t & 63;
  int wm = w >> 2, wn = w & 3;
  int b = blockIdx.z;
  int n0 = blockIdx.x * 192;
  int m0 = blockIdx.y * 128;

  int fr = l & 15, fkc = l >> 4;
  const size_t bOff = (size_t)b * HW;

  auto stage = [&](int ks, int slot) {
    int k0 = ks * 32;
#pragma unroll
    for (int c = 0; c < 5; ++c) {
      int i = w * 5 + c;
      const u16* g;
      u16* d;
      if (i < 8) {
        g = Ah + (size_t)(m0 + i * 16 + fr) * K + k0 + fkc * 8;
        d = &smem[slot * 8192 + i * 512];
      } else if (i < 16) {
        g = Al + (size_t)(m0 + (i - 8) * 16 + fr) * K + k0 + fkc * 8;
        d = &smem[slot * 8192 + i * 512];
      } else if (i < 28) {
        g = Bh + (bOff + n0 + (i - 16) * 16 + fr) * (size_t)K + k0 + fkc * 8;
        d = &smem[24576 + slot * 12288 + (i - 16) * 512];
      } else {
        g = Bl + (bOff + n0 + (i - 28) * 16 + fr) * (size_t)K + k0 + fkc * 8;
        d = &smem[24576 + slot * 12288 + (i - 16) * 512];
      }
      async16(d, g);
    }
  };

  f32x4 acc[4][3];
#pragma unroll
  for (int i = 0; i < 4; ++i)
#pragma unroll
    for (int j = 0; j < 3; ++j) acc[i][j] = (f32x4){0.f, 0.f, 0.f, 0.f};

  stage(0, 0);
  stage(1, 1);

  for (int ks = 0; ks < NSTEP; ++ks) {
    if (ks + 1 < NSTEP)
      asm volatile("s_waitcnt vmcnt(5)" ::: "memory");
    else
      asm volatile("s_waitcnt vmcnt(0)" ::: "memory");
    __builtin_amdgcn_s_barrier();
    __builtin_amdgcn_sched_barrier(0);

    if (ks + 2 < NSTEP) stage(ks + 2, (ks + 2) % 3);

    int cur = ks % 3;
    bf16x8 bh[3], bl[3];
#pragma unroll
    for (int nt = 0; nt < 3; ++nt) {
      bh[nt] = *(const bf16x8*)&smem[24576 + cur * 12288 + (wn * 3 + nt) * 512 + l * 8];
      bl[nt] = *(const bf16x8*)&smem[24576 + cur * 12288 + (12 + wn * 3 + nt) * 512 + l * 8];
    }
    bf16x8 ah[4], al[4];
#pragma unroll
    for (int mt = 0; mt < 4; ++mt) {
      ah[mt] = *(const bf16x8*)&smem[cur * 8192 + (wm * 4 + mt) * 512 + l * 8];
      al[mt] = *(const bf16x8*)&smem[cur * 8192 + (8 + wm * 4 + mt) * 512 + l * 8];
    }
    __builtin_amdgcn_s_setprio(1);
#pragma unroll
    for (int mt = 0; mt < 4; ++mt)
#pragma unroll
      for (int nt = 0; nt < 3; ++nt) {
        acc[mt][nt] = __builtin_amdgcn_mfma_f32_16x16x32_bf16(ah[mt], bh[nt], acc[mt][nt], 0, 0, 0);
        acc[mt][nt] = __builtin_amdgcn_mfma_f32_16x16x32_bf16(ah[mt], bl[nt], acc[mt][nt], 0, 0, 0);
        acc[mt][nt] = __builtin_amdgcn_mfma_f32_16x16x32_bf16(al[mt], bh[nt], acc[mt][nt], 0, 0, 0);
      }
    __builtin_amdgcn_s_setprio(0);
  }

  __syncthreads();

  int q4 = (l >> 4) * 4;
#pragma unroll
  for (int mt = 0; mt < 4; ++mt) {
    int mb = m0 + (wm * 4 + mt) * 16 + q4;
    float iv[4], ad[4];
    if (BNRELU) {
      float4 g0 = *(const float4*)&p0[mb];
      float4 g1 = *(const float4*)&p1[mb];
      float4 g2 = *(const float4*)&p2[mb];
      float4 g3 = *(const float4*)&p3[mb];
      float4 g4 = *(const float4*)&p4[mb];
      iv[0] = g1.x * rsqrtf(g4.x + 1e-5f);
      iv[1] = g1.y * rsqrtf(g4.y + 1e-5f);
      iv[2] = g1.z * rsqrtf(g4.z + 1e-5f);
      iv[3] = g1.w * rsqrtf(g4.w + 1e-5f);
      ad[0] = (g0.x - g3.x) * iv[0] + g2.x;
      ad[1] = (g0.y - g3.y) * iv[1] + g2.y;
      ad[2] = (g0.z - g3.z) * iv[2] + g2.z;
      ad[3] = (g0.w - g3.w) * iv[3] + g2.w;
    } else {
      float4 g0 = *(const float4*)&p0[mb];
      ad[0] = g0.x; ad[1] = g0.y; ad[2] = g0.z; ad[3] = g0.w;
    }
#pragma unroll
    for (int nt = 0; nt < 3; ++nt) {
      int n = n0 + (wn * 3 + nt) * 16 + fr;
      float v[4];
#pragma unroll
      for (int r = 0; r < 4; ++r) {
        float x = acc[mt][nt][r];
        v[r] = BNRELU ? fmaxf(x * iv[r] + ad[r], 0.f) : x + ad[r];
        if (C) C[((size_t)(b * M_TOT) + mb + r) * HW + n] = v[r];
      }
      if (BNRELU && Th) {
        ushort4 hh, ll;
        hh.x = f2bf(v[0]); ll.x = f2bf(v[0] - bf2f(hh.x));
        hh.y = f2bf(v[1]); ll.y = f2bf(v[1] - bf2f(hh.y));
        hh.z = f2bf(v[2]); ll.z = f2bf(v[2] - bf2f(hh.z));
        hh.w = f2bf(v[3]); ll.w = f2bf(v[3] - bf2f(hh.w));
        int nl = (wn * 3 + nt) * 16 + fr;
        int ml = (wm * 4 + mt) * 16 + q4;
        *(ushort4*)&smem[nl * 136 + ml] = hh;
        *(ushort4*)&smem[26112 + nl * 136 + ml] = ll;
      }
    }
  }
  if (BNRELU && Th) {
    __syncthreads();
#pragma unroll
    for (int it = 0; it < 6; ++it) {
      int row = it * 32 + (t >> 4);
      int c8 = (t & 15) * 8;
      size_t go = (bOff + n0 + row) * (size_t)M_TOT + m0 + c8;
      *(bf16x8*)&Th[go] = *(const bf16x8*)&smem[row * 136 + c8];
      *(bf16x8*)&Tl[go] = *(const bf16x8*)&smem[26112 + row * 136 + c8];
    }
  }
}

// ---------------------------------------------------------------------------
// gemm_kq_fx: kq GEMM reading X fp32 DIRECTLY (deletes convert_t<512>).
//  C[b][m][n] = relu(BN( sum_k Wk[m][k] * x[b][k][n] )), fused kqT store.
//  A (weights, split-bf16) via global_load_lds, 3-slot ring (2 loads/wave).
//  B (x fp32) reg-staged: per thread 3 slots of (4k x 1n): 12 scalar dword
//  loads (each instr = 64 consecutive n = 256B coalesced), f2bf split in
//  reg, 2x ds_write_b64 per slot into the frag-major layout; double-buffered.
//  Counted vmcnt: per-wave in-flight per step = A[2]+B[12] = 14 (uniform).
//  Same bytes from HBM as the old xth/xtl read; convert_t round trip gone.
// ---------------------------------------------------------------------------
__global__ __launch_bounds__(512) void gemm_kq_fx(
    const u16* __restrict__ Ah, const u16* __restrict__ Al,
    const float* __restrict__ X,
    float* __restrict__ C,
    const float* __restrict__ p0, const float* __restrict__ p1,
    const float* __restrict__ p2, const float* __restrict__ p3,
    const float* __restrict__ p4,
    u16* __restrict__ Th, u16* __restrict__ Tl) {
  constexpr int NSTEP = 16;  // K=512
  // A ring: [0,24576) u16 : 3 slots x 16 frags x 512
  // B dbuf: [24576,49152) u16 : 2 bufs x 24 frags x 512
  // epilogue transpose: hi [0,26112), lo [26112,52224)
  __shared__ alignas(16) u16 smem[52224];

  int t = threadIdx.x, w = t >> 6, l = t & 63;
  int wm = w >> 2, wn = w & 3;
  int b = blockIdx.z;
  int n0 = blockIdx.x * 192;
  int m0 = blockIdx.y * 128;
  int fr = l & 15, fkc = l >> 4;
  const size_t bOff = (size_t)b * HW;
  const float* xb = X + (size_t)b * 512 * HW + n0;

  // per-thread B-slot geometry (ks-independent): slot s = t + j*512 (<1536)
  // kc4 = s/192 (k-quad 0..7), nn = s%192 (n within tile)
  int kc4v[3], nnv[3], wOffH[3];
#pragma unroll
  for (int j = 0; j < 3; ++j) {
    int s = t + j * 512;
    kc4v[j] = s / 192;
    nnv[j] = s - kc4v[j] * 192;
    // frag-major u16 offset (hi): frag = nn/16; lane = (kc4>>1)*16 + nn%16;
    // within-lane: (kc4&1)*4
    wOffH[j] = (nnv[j] >> 4) * 512 + (((kc4v[j] >> 1) * 16 + (nnv[j] & 15)) * 8) +
               (kc4v[j] & 1) * 4;
  }

  auto stageA = [&](int ks, int slot) {
    int k0 = ks * 32;
#pragma unroll
    for (int c = 0; c < 2; ++c) {
      int i = w * 2 + c;
      const u16* g = (i < 8)
          ? Ah + (size_t)(m0 + i * 16 + fr) * 512 + k0 + fkc * 8
          : Al + (size_t)(m0 + (i - 8) * 16 + fr) * 512 + k0 + fkc * 8;
      async16(&smem[slot * 8192 + i * 512], g);
    }
  };

  auto issueB = [&](int ks, float* r) {
#pragma unroll
    for (int j = 0; j < 3; ++j) {
      const float* src = xb + (size_t)(ks * 32 + kc4v[j] * 4) * HW + nnv[j];
#pragma unroll
      for (int i = 0; i < 4; ++i) r[j * 4 + i] = src[(size_t)i * HW];
    }
  };

  auto cvtB = [&](float* r, int buf) {
#pragma unroll
    for (int j = 0; j < 3; ++j) {
      ushort4 hh, ll;
      float v0 = r[j * 4 + 0], v1 = r[j * 4 + 1], v2 = r[j * 4 + 2], v3 = r[j * 4 + 3];
      hh.x = f2bf(v0); ll.x = f2bf(v0 - bf2f(hh.x));
      hh.y = f2bf(v1); ll.y = f2bf(v1 - bf2f(hh.y));
      hh.z = f2bf(v2); ll.z = f2bf(v2 - bf2f(hh.z));
      hh.w = f2bf(v3); ll.w = f2bf(v3 - bf2f(hh.w));
      int o = 24576 + buf * 12288 + wOffH[j];
      *(ushort4*)&smem[o] = hh;            // hi frags 0..11
      *(ushort4*)&smem[o + 12 * 512] = ll; // lo frags 12..23
    }
  };

  f32x4 acc[4][3];
#pragma unroll
  for (int i = 0; i < 4; ++i)
#pragma unroll
    for (int j = 0; j < 3; ++j) acc[i][j] = (f32x4){0.f, 0.f, 0.f, 0.f};

  float rB0[12], rB1[12];
  // prologue: A0,B0,A1,B1 issued (in-flight order A0[2],B0[12],A1[2],B1[12])
  stageA(0, 0); issueB(0, rB0);
  stageA(1, 1); issueB(1, rB1);
  __builtin_amdgcn_sched_barrier(0);
  asm volatile("s_waitcnt vmcnt(14)" ::: "memory");  // A0,B0 done; A1,B1 fly
  cvtB(rB0, 0);

#pragma unroll 2
  for (int ks = 0; ks < NSTEP; ++ks) {
    asm volatile("s_waitcnt lgkmcnt(0)" ::: "memory");  // cvt writes + reads done
    __builtin_amdgcn_s_barrier();   // A slot ks%3 + B buf ks&1 ready
    __builtin_amdgcn_sched_barrier(0);

    if (ks + 2 < NSTEP) {
      stageA(ks + 2, (ks + 2) % 3);
      issueB(ks + 2, (ks & 1) ? rB1 : rB0);  // B(m) lives in array[m&1]
      __builtin_amdgcn_sched_barrier(0);
    }

    int curA = ks % 3, curB = ks & 1;
    bf16x8 bh[3], bl[3];
#pragma unroll
    for (int nt = 0; nt < 3; ++nt) {
      bh[nt] = *(const bf16x8*)&smem[24576 + curB * 12288 + (wn * 3 + nt) * 512 + l * 8];
      bl[nt] = *(const bf16x8*)&smem[24576 + curB * 12288 + (12 + wn * 3 + nt) * 512 + l * 8];
    }
    bf16x8 ah[4], al[4];
#pragma unroll
    for (int mt = 0; mt < 4; ++mt) {
      ah[mt] = *(const bf16x8*)&smem[curA * 8192 + (wm * 4 + mt) * 512 + l * 8];
      al[mt] = *(const bf16x8*)&smem[curA * 8192 + (8 + wm * 4 + mt) * 512 + l * 8];
    }
    __builtin_amdgcn_s_setprio(1);
#pragma unroll
    for (int mt = 0; mt < 4; ++mt)
#pragma unroll
      for (int nt = 0; nt < 3; ++nt) {
        acc[mt][nt] = __builtin_amdgcn_mfma_f32_16x16x32_bf16(ah[mt], bh[nt], acc[mt][nt], 0, 0, 0);
        acc[mt][nt] = __builtin_amdgcn_mfma_f32_16x16x32_bf16(ah[mt], bl[nt], acc[mt][nt], 0, 0, 0);
        acc[mt][nt] = __builtin_amdgcn_mfma_f32_16x16x32_bf16(al[mt], bh[nt], acc[mt][nt], 0, 0, 0);
      }
    __builtin_amdgcn_s_setprio(0);

    if (ks + 1 < NSTEP) {
      if (ks + 2 < NSTEP)
        asm volatile("s_waitcnt vmcnt(14)" ::: "memory");  // drain A(ks+1),B(ks+1)
      else
        asm volatile("s_waitcnt vmcnt(0)" ::: "memory");
      cvtB((ks & 1) ? rB0 : rB1, (ks + 1) & 1);  // B(ks+1) = array[(ks+1)&1]
    }
  }

  __syncthreads();  // ring reads done before epilogue reuses smem

  int q4 = (l >> 4) * 4;
#pragma unroll
  for (int mt = 0; mt < 4; ++mt) {
    int mb = m0 + (wm * 4 + mt) * 16 + q4;
    float iv[4], ad[4];
    {
      float4 g0 = *(const float4*)&p0[mb];
      float4 g1 = *(const float4*)&p1[mb];
      float4 g2 = *(const float4*)&p2[mb];
      float4 g3 = *(const float4*)&p3[mb];
      float4 g4 = *(const float4*)&p4[mb];
      iv[0] = g1.x * rsqrtf(g4.x + 1e-5f);
      iv[1] = g1.y * rsqrtf(g4.y + 1e-5f);
      iv[2] = g1.z * rsqrtf(g4.z + 1e-5f);
      iv[3] = g1.w * rsqrtf(g4.w + 1e-5f);
      ad[0] = (g0.x - g3.x) * iv[0] + g2.x;
      ad[1] = (g0.y - g3.y) * iv[1] + g2.y;
      ad[2] = (g0.z - g3.z) * iv[2] + g2.z;
      ad[3] = (g0.w - g3.w) * iv[3] + g2.w;
    }
#pragma unroll
    for (int nt = 0; nt < 3; ++nt) {
      int n = n0 + (wn * 3 + nt) * 16 + fr;
      float v[4];
#pragma unroll
      for (int r = 0; r < 4; ++r) {
        float x = acc[mt][nt][r];
        v[r] = fmaxf(x * iv[r] + ad[r], 0.f);
        if (C) C[((size_t)(b * 256) + mb + r) * HW + n] = v[r];
      }
      ushort4 hh, ll;
      hh.x = f2bf(v[0]); ll.x = f2bf(v[0] - bf2f(hh.x));
      hh.y = f2bf(v[1]); ll.y = f2bf(v[1] - bf2f(hh.y));
      hh.z = f2bf(v[2]); ll.z = f2bf(v[2] - bf2f(hh.z));
      hh.w = f2bf(v[3]); ll.w = f2bf(v[3] - bf2f(hh.w));
      int nl = (wn * 3 + nt) * 16 + fr;
      int ml = (wm * 4 + mt) * 16 + q4;
      *(ushort4*)&smem[nl * 136 + ml] = hh;
      *(ushort4*)&smem[26112 + nl * 136 + ml] = ll;
    }
  }
  __syncthreads();
#pragma unroll
  for (int it = 0; it < 6; ++it) {
    int row = it * 32 + (t >> 4);
    int c8 = (t & 15) * 8;
    size_t go = (bOff + n0 + row) * (size_t)256 + m0 + c8;
    *(bf16x8*)&Th[go] = *(const bf16x8*)&smem[row * 136 + c8];
    *(bf16x8*)&Tl[go] = *(const bf16x8*)&smem[26112 + row * 136 + c8];
  }
}

// ---------------------------------------------------------------------------
// Pyramid-pool kq from kqT split-bf16 -> keypsum[b][110][256] (SUMS).
// ---------------------------------------------------------------------------
__global__ __launch_bounds__(256) void pool_kqt(const u16* __restrict__ kqth,
                                                const u16* __restrict__ kqtl,
                                                float* __restrict__ keypsum) {
  int cq = blockIdx.x, band = blockIdx.y, b = blockIdx.z;
  int t = threadIdx.x;
  int row0 = band * 5, col0 = cq * 30;
  int r3 = row0 / 40, r6 = row0 / 20, r8 = row0 / 15;
  float* base = keypsum + (size_t)b * 110 * 256 + t;
  float s1 = 0.f, s3 = 0.f, s6 = 0.f, s8 = 0.f;
  int b3 = -1, b6 = -1, b8 = -1;
  for (int cc = 0; cc < 30; ++cc) {
    int col = col0 + cc;
    float v = 0.f;
#pragma unroll
    for (int r = 0; r < 5; ++r) {
      size_t o = ((size_t)(b * HW + (row0 + r) * 120 + col)) * 256 + t;
      v += bf2f(kqth[o]) + bf2f(kqtl[o]);
    }
    int i3 = 1 + r3 * 3 + col / 40;
    int i6 = 10 + r6 * 6 + col / 20;
    int i8 = 46 + r8 * 8 + col / 15;
    s1 += v;
    if (i3 != b3) { if (b3 >= 0) atomicAdd(base + (size_t)b3 * 256, s3); s3 = 0.f; b3 = i3; }
    s3 += v;
    if (i6 != b6) { if (b6 >= 0) atomicAdd(base + (size_t)b6 * 256, s6); s6 = 0.f; b6 = i6; }
    s6 += v;
    if (i8 != b8) { if (b8 >= 0) atomicAdd(base + (size_t)b8 * 256, s8); s8 = 0.f; b8 = i8; }
    s8 += v;
  }
  atomicAdd(base, s1);
  atomicAdd(base + (size_t)b3 * 256, s3);
  atomicAdd(base + (size_t)b6 * 256, s6);
  atomicAdd(base + (size_t)b8 * 256, s8);
}

// ---------------------------------------------------------------------------
// valueT[b][cv][128] hi/lo = Wv[cv,:] . xp[b,:,s] + bv[cv]  (s>=110 -> 0)
// ---------------------------------------------------------------------------
__global__ __launch_bounds__(256) void value_kernel(
    const float* __restrict__ Wv, const float* __restrict__ xp,
    const float* __restrict__ bv, u16* __restrict__ vth,
    u16* __restrict__ vtl) {
  int b = blockIdx.x >> 7, s = blockIdx.x & 127;
  int t = threadIdx.x;
  size_t o = ((size_t)(b * 256 + t)) * 128 + s;
  if (s >= S_TOT) { vth[o] = 0; vtl[o] = 0; return; }
  __shared__ float xs[512];
  for (int i = t; i < 512; i += 256) xs[i] = xp[((size_t)b * 512 + i) * S_TOT + s];
  __syncthreads();
  float accv = 0.f;
  const float* wv = Wv + (size_t)t * 512;
  for (int k = 0; k < 512; k += 4) {
    float4 w4 = *(const float4*)&wv[k];
    accv += w4.x * xs[k] + w4.y * xs[k + 1] + w4.z * xs[k + 2] + w4.w * xs[k + 3];
  }
  accv += bv[t];
  u16 h = f2bf(accv);
  vth[o] = h;
  vtl[o] = f2bf(accv - bf2f(h));
}

// ---------------------------------------------------------------------------
// keypT[b][128][256] hi/lo. SUMLAYOUT=1: keypsum[b][110][256] sums;
// SUMLAYOUT=0: keyp[b][256][110] means. s>=110 -> 0.
// ---------------------------------------------------------------------------
template <int SUMLAYOUT>
__global__ __launch_bounds__(256) void convert_key(const float* __restrict__ keyp,
                                                   u16* __restrict__ kth,
                                                   u16* __restrict__ ktl) {
  int b = blockIdx.x;
  int t = threadIdx.x;
  for (int i = t; i < 128 * 256; i += 256) {
    int s = i >> 8, c = i & 255;
    float v = 0.f;
    if (s < S_TOT) {
      if (SUMLAYOUT)
        v = keyp[((size_t)(b * 110 + s)) * 256 + c] * pool_scale(s);
      else
        v = keyp[((size_t)(b * 256 + c)) * S_TOT + s];
    }
    u16 h = f2bf(v);
    size_t o = ((size_t)(b * 128 + s)) * 256 + c;
    kth[o] = h;
    ktl[o] = f2bf(v - bf2f(h));
  }
}

// ---------------------------------------------------------------------------
// MFMA attention v2. Per block: 64 pixels, 4 waves. (unchanged)
// ---------------------------------------------------------------------------
__global__ __launch_bounds__(256) void attn_mfma(
    const u16* __restrict__ qh, const u16* __restrict__ ql,
    const u16* __restrict__ kh, const u16* __restrict__ kl,
    const u16* __restrict__ vh, const u16* __restrict__ vl,
    u16* __restrict__ aggh, u16* __restrict__ aggl) {
  __shared__ alignas(16) u16 lds[17408];
  int b = blockIdx.y, pix0 = blockIdx.x * 64;
  int t = threadIdx.x, w = t >> 6, l = t & 63;
  int fr = l & 15, q = l >> 4;

  const u16* kbase_h = kh + (size_t)b * 128 * 256;
  const u16* kbase_l = kl + (size_t)b * 128 * 256;

  f32x4 acc[8];
#pragma unroll
  for (int st = 0; st < 8; ++st) acc[st] = (f32x4){0.f, 0.f, 0.f, 0.f};

  const u16* qbh = qh + ((size_t)(b * HW + pix0 + w * 16 + fr)) * 256 + q * 8;
  const u16* qbl = ql + ((size_t)(b * HW + pix0 + w * 16 + fr)) * 256 + q * 8;

  auto stageK = [&](int ks, int buf) {
    int c0 = ks * 32;
#pragma unroll
    for (int j = 0; j < 4; ++j) {
      int i = t + j * 256;
      int half = i >> 9;
      int idx = i & 511;
      int st = idx >> 6, ll = idx & 63;
      const u16* src = (half ? kbase_l : kbase_h) +
                       (st * 16 + (ll & 15)) * 256 + c0 + (ll >> 4) * 8;
      async16(&lds[buf * 8192 + half * 4096 + idx * 8], src);
    }
  };

  stageK(0, 0);
  for (int ks = 0; ks < 8; ++ks) {
    __syncthreads();
    if (ks < 7) stageK(ks + 1, (ks + 1) & 1);
    bf16x8 ah = *(const bf16x8*)(qbh + ks * 32);
    bf16x8 al = *(const bf16x8*)(qbl + ks * 32);
    const u16* kb = &lds[(ks & 1) * 8192 + l * 8];
#pragma unroll
    for (int st = 0; st < 8; ++st) {
      bf16x8 bh = *(const bf16x8*)(kb + st * 512);
      bf16x8 bl = *(const bf16x8*)(kb + 4096 + st * 512);
      acc[st] = __builtin_amdgcn_mfma_f32_16x16x32_bf16(ah, bh, acc[st], 0, 0, 0);
      acc[st] = __builtin_amdgcn_mfma_f32_16x16x32_bf16(ah, bl, acc[st], 0, 0, 0);
      acc[st] = __builtin_amdgcn_mfma_f32_16x16x32_bf16(al, bh, acc[st], 0, 0, 0);
    }
  }

#pragma unroll
  for (int st = 0; st < 8; ++st)
#pragma unroll
    for (int r = 0; r < 4; ++r) acc[st][r] *= 0.0625f;
  if (fr >= 14) {
#pragma unroll
    for (int r = 0; r < 4; ++r) acc[6][r] = -1e30f;
  }
#pragma unroll
  for (int r = 0; r < 4; ++r) acc[7][r] = -1e30f;

#pragma unroll
  for (int r = 0; r < 4; ++r) {
    float m = -1e30f;
#pragma unroll
    for (int st = 0; st < 8; ++st) m = fmaxf(m, acc[st][r]);
    m = fmaxf(m, __shfl_xor(m, 1));
    m = fmaxf(m, __shfl_xor(m, 2));
    m = fmaxf(m, __shfl_xor(m, 4));
    m = fmaxf(m, __shfl_xor(m, 8));
    float s = 0.f;
#pragma unroll
    for (int st = 0; st < 8; ++st) {
      float e = __expf(acc[st][r] - m);
      acc[st][r] = e;
      s += e;
    }
    s += __shfl_xor(s, 1);
    s += __shfl_xor(s, 2);
    s += __shfl_xor(s, 4);
    s += __shfl_xor(s, 8);
    float inv = 1.f / s;
#pragma unroll
    for (int st = 0; st < 8; ++st) acc[st][r] *= inv;
  }

  __syncthreads();

  int prow = w * 16 + q * 4;
#pragma unroll
  for (int st = 0; st < 8; ++st) {
    int s = st * 16 + fr;
#pragma unroll
    for (int r = 0; r < 4; ++r) {
      float v = acc[st][r];
      u16 h = f2bf(v);
      lds[(prow + r) * 136 + s] = h;
      lds[8704 + (prow + r) * 136 + s] = f2bf(v - bf2f(h));
    }
  }
  __syncthreads();

  f32x4 oacc[4][4];
#pragma unroll
  for (int nt = 0; nt < 4; ++nt)
#pragma unroll
    for (int pt = 0; pt < 4; ++pt) oacc[nt][pt] = (f32x4){0.f, 0.f, 0.f, 0.f};

  const u16* vbh = vh + ((size_t)(b * 256 + w * 64 + fr)) * 128 + q * 8;
  const u16* vbl = vl + ((size_t)(b * 256 + w * 64 + fr)) * 128 + q * 8;

#pragma unroll
  for (int kc = 0; kc < 4; ++kc) {
    bf16x8 ph[4], pl[4];
#pragma unroll
    for (int pt = 0; pt < 4; ++pt) {
      ph[pt] = *(const bf16x8*)&lds[(pt * 16 + fr) * 136 + kc * 32 + q * 8];
      pl[pt] = *(const bf16x8*)&lds[8704 + (pt * 16 + fr) * 136 + kc * 32 + q * 8];
    }
#pragma unroll
    for (int nt = 0; nt < 4; ++nt) {
      bf16x8 a_h = *(const bf16x8*)(vbh + (size_t)nt * 16 * 128 + kc * 32);
      bf16x8 a_l = *(const bf16x8*)(vbl + (size_t)nt * 16 * 128 + kc * 32);
#pragma unroll
      for (int pt = 0; pt < 4; ++pt) {
        oacc[nt][pt] = __builtin_amdgcn_mfma_f32_16x16x32_bf16(a_h, ph[pt], oacc[nt][pt], 0, 0, 0);
        oacc[nt][pt] = __builtin_amdgcn_mfma_f32_16x16x32_bf16(a_h, pl[pt], oacc[nt][pt], 0, 0, 0);
        oacc[nt][pt] = __builtin_amdgcn_mfma_f32_16x16x32_bf16(a_l, ph[pt], oacc[nt][pt], 0, 0, 0);
      }
    }
  }

#pragma unroll
  for (int nt = 0; nt < 4; ++nt) {
#pragma unroll
    for (int pt = 0; pt < 4; ++pt) {
      ushort4 oh, ol;
      float v0 = oacc[nt][pt][0], v1 = oacc[nt][pt][1];
      float v2 = oacc[nt][pt][2], v3 = oacc[nt][pt][3];
      oh.x = f2bf(v0); ol.x = f2bf(v0 - bf2f(oh.x));
      oh.y = f2bf(v1); ol.y = f2bf(v1 - bf2f(oh.y));
      oh.z = f2bf(v2); ol.z = f2bf(v2 - bf2f(oh.z));
      oh.w = f2bf(v3); ol.w = f2bf(v3 - bf2f(oh.w));
      size_t o = ((size_t)(b * HW + pix0 + pt * 16 + fr)) * 256 + (w * 4 + nt) * 16 + q * 4;
      *(ushort4*)&aggh[o] = oh;
      *(ushort4*)&aggl[o] = ol;
    }
  }
}

extern "C" void kernel_launch(void* const* d_in, const int* in_sizes, int n_in,
                              void* d_out, int out_size, void* d_ws, size_t ws_size,
                              hipStream_t stream) {
  (void)in_sizes; (void)n_in; (void)out_size;
  const float* x     = (const float*)d_in[0];
  const float* Wk    = (const float*)d_in[1];
  const float* bk    = (const float*)d_in[2];
  const float* gamma = (const float*)d_in[3];
  const float* beta  = (const float*)d_in[4];
  const float* mean  = (const float*)d_in[5];
  const float* var   = (const float*)d_in[6];
  const float* Wv    = (const float*)d_in[7];
  const float* bv    = (const float*)d_in[8];
  const float* Wo    = (const float*)d_in[9];
  const float* bo    = (const float*)d_in[10];
  float* out = (float*)d_out;

  char* p = (char*)d_ws;
  float* kq = (float*)p;      p += (size_t)14745600 * 4;   // fp32 kq (fallback only)
  u16* xth = (u16*)p;         p += (size_t)29491200 * 2;   // fallback / agg alias
  u16* xtl = (u16*)p;         p += (size_t)29491200 * 2;
  u16* wkh = (u16*)p;         p += 131072 * 2;
  u16* wkl = (u16*)p;         p += 131072 * 2;
  u16* woh = (u16*)p;         p += 131072 * 2;
  u16* wol = (u16*)p;         p += 131072 * 2;
  float* xp = (float*)p;      p += (size_t)4 * 512 * 110 * 4;   // pooled-x means
  float* keypsum = (float*)p; p += (size_t)4 * 110 * 256 * 4;   // pooled-kq sums
  u16* vth = (u16*)p;         p += (size_t)4 * 256 * 128 * 2;
  u16* vtl = (u16*)p;         p += (size_t)4 * 256 * 128 * 2;
  u16* kth = (u16*)p;         p += (size_t)4 * 128 * 256 * 2;
  u16* ktl = (u16*)p;         p += (size_t)4 * 128 * 256 * 2;
  u16* kqth_f = (u16*)p;      p += (size_t)14745600 * 2;   // 4*14400*256 bf16
  u16* kqtl_f = (u16*)p;      p += (size_t)14745600 * 2;
  bool fused = ((size_t)(p - (char*)d_ws) <= ws_size);

  u16* aggh = xth;
  u16* aggl = xtl;
  u16* kqth = fused ? kqth_f : xth + (size_t)14745600;
  u16* kqtl = fused ? kqtl_f : xtl + (size_t)14745600;

  if (fused)
    hipMemsetAsync(keypsum, 0, (size_t)4 * 110 * 256 * 4, stream);

  // weight splits
  convert_w<<<512, 256, 0, stream>>>(Wk, wkh, wkl, 256 * 512);
  convert_w<<<512, 256, 0, stream>>>(Wo, woh, wol, 512 * 256);
  // pyramid-pool x (pooling commutes with 1x1 conv for value)
  pool_kernel<<<dim3(4 * 512), dim3(256), 0, stream>>>(x, xp);
  // valueT = split(conv_v(pooled x) + bv), s-padded
  value_kernel<<<dim3(4 * 128), 256, 0, stream>>>(Wv, xp, bv, vth, vtl);
  if (fused) {
    // kq GEMM directly from x fp32 (no convert_t<512>); fused kqT store
    gemm_kq_fx<<<dim3(75, 2, 4), 512, 0, stream>>>(
        wkh, wkl, x, nullptr, bk, gamma, beta, mean, var, kqth, kqtl);
    pool_kqt<<<dim3(4, 24, 4), 256, 0, stream>>>(kqth, kqtl, keypsum);
    convert_key<1><<<dim3(4), dim3(256), 0, stream>>>(keypsum, kth, ktl);
  } else {
    convert_t<512><<<dim3(225, 8, 4), 256, 0, stream>>>(x, xth, xtl);
    gemm_mfma<512, 256, true><<<dim3(75, 2, 4), 512, 0, stream>>>(
        wkh, wkl, xth, xtl, kq, bk, gamma, beta, mean, var, kqth, kqtl);
    convert_t<256><<<dim3(225, 4, 4), 256, 0, stream>>>(kq, kqth, kqtl);
    pool_kernel<<<dim3(4 * 256), dim3(256), 0, stream>>>(kq, keypsum);
    convert_key<0><<<dim3(4), dim3(256), 0, stream>>>(keypsum, kth, ktl);
  }
  // fused MFMA attention -> agg split bf16
  attn_mfma<<<dim3(225, 4), 256, 0, stream>>>(kqth, kqtl, kth, ktl, vth, vtl,
                                              aggh, aggl);
  // out = conv_out(agg) + bo  [ring-pipelined]
  gemm_mfma<256, 512, false><<<dim3(75, 4, 4), 512, 0, stream>>>(
      woh, wol, aggh, aggl, out, bo, nullptr, nullptr, nullptr, nullptr,
      nullptr, nullptr);
}